// Round 1
// baseline (358.783 us; speedup 1.0000x reference)
//
#include <hip/hip_runtime.h>
#include <stdint.h>

typedef unsigned short ushort_t;
typedef __bf16 bf16x8 __attribute__((ext_vector_type(8)));
typedef float f32x4 __attribute__((ext_vector_type(4)));
typedef unsigned int u32;

// ---------- bf16 helpers (manual, RNE) ----------
__device__ __forceinline__ float bf2f(ushort_t u) {
    union { u32 u; float f; } x; x.u = ((u32)u) << 16; return x.f;
}
__device__ __forceinline__ ushort_t f2bf(float f) {
    union { float f; u32 u; } x; x.f = f;
    u32 r = x.u + 0x7FFFu + ((x.u >> 16) & 1u);
    return (ushort_t)(r >> 16);
}

// ---------- async global->LDS, 16B per lane ----------
__device__ __forceinline__ void async16(const void* gp, void* lp) {
    __builtin_amdgcn_global_load_lds(
        (const __attribute__((address_space(1))) u32*)(gp),
        (__attribute__((address_space(3))) u32*)(lp),
        16, 0, 0);
}

// ---------- fp32 -> bf16 cast (vectorized) ----------
__global__ __launch_bounds__(256) void cvt_bf16_kernel(
    const float* __restrict__ in, ushort_t* __restrict__ out, int n)
{
    int i = (blockIdx.x * 256 + threadIdx.x) * 4;
    if (i >= n) return;
    float4 v = *reinterpret_cast<const float4*>(in + i);
    ushort4 o;
    o.x = f2bf(v.x); o.y = f2bf(v.y); o.z = f2bf(v.z); o.w = f2bf(v.w);
    *reinterpret_cast<ushort4*>(out + i) = o;
}

// ---------- concatenated qkv bias ----------
__global__ void build_bcat_kernel(const float* __restrict__ bq,
                                  const float* __restrict__ bk,
                                  const float* __restrict__ bv,
                                  float* __restrict__ bcat)
{
    int i = blockIdx.x * 256 + threadIdx.x;   // 0..4095
    float v = (i < 2048) ? bq[i] : (i < 3072) ? bk[i - 2048] : bv[i - 3072];
    bcat[i] = v;
}

// ---------- m97-style bf16 GEMM:  C[M,N] = A[M,K] @ B[N,K]^T + bias ----------
// 128x128 tile, BK=32, 256 threads (4 waves, each 64x64 via 4x4 16x16 frags)
template<bool STORE_BF16>
__global__ __launch_bounds__(256) void gemm_bt_kernel(
    const ushort_t* __restrict__ A, const ushort_t* __restrict__ B,
    const float* __restrict__ bias, void* __restrict__ C,
    int M, int N, int K)
{
    __shared__ alignas(16) ushort_t lds_a[128 * 32];
    __shared__ alignas(16) ushort_t lds_b[128 * 32];

    const int tid  = threadIdx.x;
    const int wid  = tid >> 6;
    const int lane = tid & 63;
    const int m0 = blockIdx.y * 128;
    const int n0 = blockIdx.x * 128;
    const int wr = (wid >> 1) * 64;   // wave row offset in tile
    const int wc = (wid & 1) * 64;    // wave col offset in tile

    // staging: thread t loads 16B: tile row t/4, k-col (t%4)*8 (two halves)
    const int srow = tid >> 2;
    const int scol = (tid & 3) << 3;
    const ushort_t* ga0 = A + (size_t)(m0 + srow) * K + scol;
    const ushort_t* ga1 = ga0 + (size_t)64 * K;
    const ushort_t* gb0 = B + (size_t)(n0 + srow) * K + scol;
    const ushort_t* gb1 = gb0 + (size_t)64 * K;
    ushort_t* la0 = lds_a + wid * 512;          // wave-uniform LDS base (bytes: wid*1024)
    ushort_t* la1 = la0 + 2048;                 // +4096B (rows 64..127)
    ushort_t* lb0 = lds_b + wid * 512;
    ushort_t* lb1 = lb0 + 2048;

    f32x4 acc[4][4] = {};

    const int fr = lane & 15;          // row within 16x16 fragment
    const int fk = (lane >> 4) << 3;   // k offset: lane-group * 8

    for (int kt = 0; kt < K; kt += 32) {
        async16(ga0 + kt, la0);
        async16(ga1 + kt, la1);
        async16(gb0 + kt, lb0);
        async16(gb1 + kt, lb1);
        __syncthreads();   // compiler drains vmcnt before barrier

        bf16x8 af[4], bfv[4];
#pragma unroll
        for (int m = 0; m < 4; ++m)
            af[m] = *reinterpret_cast<const bf16x8*>(&lds_a[(wr + m * 16 + fr) * 32 + fk]);
#pragma unroll
        for (int n = 0; n < 4; ++n)
            bfv[n] = *reinterpret_cast<const bf16x8*>(&lds_b[(wc + n * 16 + fr) * 32 + fk]);
#pragma unroll
        for (int m = 0; m < 4; ++m)
#pragma unroll
            for (int n = 0; n < 4; ++n)
                acc[m][n] = __builtin_amdgcn_mfma_f32_16x16x32_bf16(
                    af[m], bfv[n], acc[m][n], 0, 0, 0);
        __syncthreads();
    }

    // epilogue: C/D layout (verified): col = lane&15, row = (lane>>4)*4 + reg
    const int crow0 = (lane >> 4) << 2;
#pragma unroll
    for (int m = 0; m < 4; ++m) {
#pragma unroll
        for (int n = 0; n < 4; ++n) {
            const int col = n0 + wc + n * 16 + fr;
            const float bs = bias[col];
#pragma unroll
            for (int r = 0; r < 4; ++r) {
                const int row = m0 + wr + m * 16 + crow0 + r;
                const float v = acc[m][n][r] + bs;
                if (STORE_BF16)
                    ((ushort_t*)C)[(size_t)row * N + col] = f2bf(v);
                else
                    ((float*)C)[(size_t)row * N + col] = v;
            }
        }
    }
}

// ---------- per-token: RoPE + normalize + random features + head contraction ----------
// qkv row layout (bf16): [0..2047]=q (h*128+d), [2048..3071]=k, [3072..4095]=v
// writes ctx in the reference's SCRAMBLED reshape layout:
//   ctx[b*2048 + h*128 + s/16][ (s%16)*128 + d ] = out_head[b,h,s,d]
__global__ __launch_bounds__(256) void attn_kernel(
    const ushort_t* __restrict__ qkv, const float* __restrict__ R,
    ushort_t* __restrict__ ctx)
{
    __shared__ float Rt[128][65];    // R transposed, padded: Rt[d][e] = R[e][d]
    __shared__ float cs[128];
    __shared__ float sn[128];
    __shared__ float xn[24][128];    // 16 q heads + 8 k heads (roped/normed, then feats)
    __shared__ float pbuf[24][64];
    __shared__ float vsm[8][128];
    __shared__ float Am[16][8];

    const int tok = blockIdx.x;
    const int b = tok >> 11;
    const int s = tok & 2047;
    const int tid = threadIdx.x;

    // stage R transposed (coalesced read, padded conflict-free write)
    for (int idx = tid; idx < 8192; idx += 256) {
        int e = idx >> 7, d = idx & 127;
        Rt[d][e] = R[idx];
    }
    // rope tables: inv_freq[i] = 10000^(-i/64), cos/sin of s*inv_freq
    if (tid < 128) {
        int i = tid & 63;
        float invf = __expf(-(float)i * (9.210340371976184f / 64.0f));
        float ang = (float)s * invf;
        sn[tid] = sinf(ang);
        cs[tid] = cosf(ang);
    }
    const ushort_t* qrow = qkv + (size_t)tok * 4096;
    for (int idx = tid; idx < 1024; idx += 256)
        vsm[idx >> 7][idx & 127] = bf2f(qrow[3072 + idx]);
    __syncthreads();

    // RoPE on q (16 heads) and k (8 heads)
    for (int idx = tid; idx < 3072; idx += 256) {
        int vec = idx >> 7, d = idx & 127;
        int base = (vec < 16) ? vec * 128 : 2048 + (vec - 16) * 128;
        float x  = bf2f(qrow[base + d]);
        int dro  = (d < 64) ? d + 64 : d - 64;
        float xr = bf2f(qrow[base + dro]);
        if (d < 64) xr = -xr;
        xn[vec][d] = x * cs[d] + xr * sn[d];
    }
    __syncthreads();

    // normalize each 128-vector to unit norm (clamped at 1e-6)
    const int wid = tid >> 6, lane = tid & 63;
    for (int vec = wid; vec < 24; vec += 4) {
        float a = xn[vec][lane], c = xn[vec][lane + 64];
        float ss2 = a * a + c * c;
        for (int off = 32; off; off >>= 1) ss2 += __shfl_down(ss2, off);
        ss2 = __shfl(ss2, 0);
        float inv = 1.0f / fmaxf(sqrtf(ss2), 1e-6f);
        xn[vec][lane]      = a * inv;
        xn[vec][lane + 64] = c * inv;
    }
    __syncthreads();

    // p[vec][e] = <xn[vec], R[e]>   (Rt reads: lanes vary e -> conflict-free)
    for (int idx = tid; idx < 1536; idx += 256) {
        int vec = idx >> 6, e = idx & 63;
        float acc = 0.f;
#pragma unroll 8
        for (int d = 0; d < 128; ++d) acc = fmaf(xn[vec][d], Rt[d][e], acc);
        pbuf[vec][e] = acc;
    }
    __syncthreads();

    // feats = [sin(p), cos(p)] / sqrt(128), overwrite xn
    for (int idx = tid; idx < 3072; idx += 256) {
        int vec = idx >> 7, d = idx & 127;
        float p = pbuf[vec][d & 63];
        float f = (d < 64) ? sinf(p) : cosf(p);
        xn[vec][d] = f * 0.08838834764831845f;
    }
    __syncthreads();

    // A[h][hk] = <qp[h], kp[hk]>
    if (tid < 128) {
        int h = tid >> 3, hk = tid & 7;
        float acc = 0.f;
#pragma unroll 8
        for (int f = 0; f < 128; ++f) acc = fmaf(xn[h][f], xn[16 + hk][f], acc);
        Am[h][hk] = acc;
    }
    __syncthreads();

    // out[h][d] = 2 * sum_hk A[h][hk] * v[hk][d]; scrambled store
    for (int idx = tid; idx < 2048; idx += 256) {
        int h = idx >> 7, d = idx & 127;
        float acc = 0.f;
#pragma unroll
        for (int hk = 0; hk < 8; ++hk) acc = fmaf(Am[h][hk], vsm[hk][d], acc);
        acc *= 2.0f;
        int row = (b << 11) + (h << 7) + (s >> 4);
        int col = ((s & 15) << 7) + d;
        ctx[(size_t)row * 2048 + col] = f2bf(acc);
    }
}

// ---------- launch ----------
extern "C" void kernel_launch(void* const* d_in, const int* in_sizes, int n_in,
                              void* d_out, int out_size, void* d_ws, size_t ws_size,
                              hipStream_t stream)
{
    const float* hs = (const float*)d_in[0];
    const float* Wq = (const float*)d_in[1];
    const float* bq = (const float*)d_in[2];
    const float* Wk = (const float*)d_in[3];
    const float* bk = (const float*)d_in[4];
    const float* Wv = (const float*)d_in[5];
    const float* bv = (const float*)d_in[6];
    const float* Wo = (const float*)d_in[7];
    const float* bo = (const float*)d_in[8];
    const float* Rm = (const float*)d_in[9];
    float* out = (float*)d_out;

    char* ws = (char*)d_ws;
    ushort_t* Xb   = (ushort_t*)(ws);                 // 4096x2048 bf16 (16.78 MB)
    ushort_t* Wcat = (ushort_t*)(ws + 16777216);      // 4096x2048 bf16 (Wq;Wk;Wv)
    ushort_t* Wo16 = (ushort_t*)(ws + 33554432);      // 2048x2048 bf16
    ushort_t* qkv  = (ushort_t*)(ws + 41943040);      // 4096x4096 bf16
    ushort_t* ctx  = (ushort_t*)(ws + 75497472);      // 4096x2048 bf16 (scrambled)
    float*    bcat = (float*)   (ws + 92274688);      // 4096 f32

    // casts to bf16
    cvt_bf16_kernel<<<8192, 256, 0, stream>>>(hs, Xb, 8388608);
    cvt_bf16_kernel<<<4096, 256, 0, stream>>>(Wq, Wcat, 4194304);
    cvt_bf16_kernel<<<2048, 256, 0, stream>>>(Wk, Wcat + 4194304, 2097152);
    cvt_bf16_kernel<<<2048, 256, 0, stream>>>(Wv, Wcat + 6291456, 2097152);
    cvt_bf16_kernel<<<4096, 256, 0, stream>>>(Wo, Wo16, 4194304);
    build_bcat_kernel<<<16, 256, 0, stream>>>(bq, bk, bv, bcat);

    // qkv = X @ [Wq;Wk;Wv]^T + bcat   (M=4096, N=4096, K=2048)
    gemm_bt_kernel<true><<<dim3(32, 32), 256, 0, stream>>>(
        Xb, Wcat, bcat, qkv, 4096, 4096, 2048);

    // per-token performer attention -> scrambled ctx
    attn_kernel<<<4096, 256, 0, stream>>>(qkv, Rm, ctx);

    // out = ctx @ Wo^T + bo   (M=4096, N=2048, K=2048), fp32 out
    gemm_bt_kernel<false><<<dim3(16, 32), 256, 0, stream>>>(
        ctx, Wo16, bo, out, 4096, 2048, 2048);
}

// Round 2
// 238.518 us; speedup vs baseline: 1.5042x; 1.5042x over previous
//
#include <hip/hip_runtime.h>
#include <stdint.h>

typedef unsigned short ushort_t;
typedef __bf16 bf16x8 __attribute__((ext_vector_type(8)));
typedef float f32x4 __attribute__((ext_vector_type(4)));
typedef unsigned int u32;

// ---------- bf16 helpers (manual, RNE) ----------
__device__ __forceinline__ float bf2f(ushort_t u) {
    union { u32 u; float f; } x; x.u = ((u32)u) << 16; return x.f;
}
__device__ __forceinline__ ushort_t f2bf(float f) {
    union { float f; u32 u; } x; x.f = f;
    u32 r = x.u + 0x7FFFu + ((x.u >> 16) & 1u);
    return (ushort_t)(r >> 16);
}

// ---------- async global->LDS, 16B per lane ----------
__device__ __forceinline__ void async16(const void* gp, void* lp) {
    __builtin_amdgcn_global_load_lds(
        (const __attribute__((address_space(1))) u32*)(gp),
        (__attribute__((address_space(3))) u32*)(lp),
        16, 0, 0);
}

// ---------- fp32 -> bf16 cast (vectorized) ----------
__global__ __launch_bounds__(256) void cvt_bf16_kernel(
    const float* __restrict__ in, ushort_t* __restrict__ out, int n)
{
    int i = (blockIdx.x * 256 + threadIdx.x) * 4;
    if (i >= n) return;
    float4 v = *reinterpret_cast<const float4*>(in + i);
    ushort4 o;
    o.x = f2bf(v.x); o.y = f2bf(v.y); o.z = f2bf(v.z); o.w = f2bf(v.w);
    *reinterpret_cast<ushort4*>(out + i) = o;
}

// ---------- concatenated qkv bias ----------
__global__ void build_bcat_kernel(const float* __restrict__ bq,
                                  const float* __restrict__ bk,
                                  const float* __restrict__ bv,
                                  float* __restrict__ bcat)
{
    int i = blockIdx.x * 256 + threadIdx.x;   // 0..4095
    float v = (i < 2048) ? bq[i] : (i < 3072) ? bk[i - 2048] : bv[i - 3072];
    bcat[i] = v;
}

// ---------- m97-style bf16 GEMM:  C[M,N] = A[M,K] @ B[N,K]^T + bias ----------
template<bool STORE_BF16>
__global__ __launch_bounds__(256) void gemm_bt_kernel(
    const ushort_t* __restrict__ A, const ushort_t* __restrict__ B,
    const float* __restrict__ bias, void* __restrict__ C,
    int M, int N, int K)
{
    __shared__ alignas(16) ushort_t lds_a[128 * 32];
    __shared__ alignas(16) ushort_t lds_b[128 * 32];

    const int tid  = threadIdx.x;
    const int wid  = tid >> 6;
    const int lane = tid & 63;
    const int m0 = blockIdx.y * 128;
    const int n0 = blockIdx.x * 128;
    const int wr = (wid >> 1) * 64;
    const int wc = (wid & 1) * 64;

    const int srow = tid >> 2;
    const int scol = (tid & 3) << 3;
    const ushort_t* ga0 = A + (size_t)(m0 + srow) * K + scol;
    const ushort_t* ga1 = ga0 + (size_t)64 * K;
    const ushort_t* gb0 = B + (size_t)(n0 + srow) * K + scol;
    const ushort_t* gb1 = gb0 + (size_t)64 * K;
    ushort_t* la0 = lds_a + wid * 512;
    ushort_t* la1 = la0 + 2048;
    ushort_t* lb0 = lds_b + wid * 512;
    ushort_t* lb1 = lb0 + 2048;

    f32x4 acc[4][4] = {};

    const int fr = lane & 15;
    const int fk = (lane >> 4) << 3;

    for (int kt = 0; kt < K; kt += 32) {
        async16(ga0 + kt, la0);
        async16(ga1 + kt, la1);
        async16(gb0 + kt, lb0);
        async16(gb1 + kt, lb1);
        __syncthreads();

        bf16x8 af[4], bfv[4];
#pragma unroll
        for (int m = 0; m < 4; ++m)
            af[m] = *reinterpret_cast<const bf16x8*>(&lds_a[(wr + m * 16 + fr) * 32 + fk]);
#pragma unroll
        for (int n = 0; n < 4; ++n)
            bfv[n] = *reinterpret_cast<const bf16x8*>(&lds_b[(wc + n * 16 + fr) * 32 + fk]);
#pragma unroll
        for (int m = 0; m < 4; ++m)
#pragma unroll
            for (int n = 0; n < 4; ++n)
                acc[m][n] = __builtin_amdgcn_mfma_f32_16x16x32_bf16(
                    af[m], bfv[n], acc[m][n], 0, 0, 0);
        __syncthreads();
    }

    const int crow0 = (lane >> 4) << 2;
#pragma unroll
    for (int m = 0; m < 4; ++m) {
#pragma unroll
        for (int n = 0; n < 4; ++n) {
            const int col = n0 + wc + n * 16 + fr;
            const float bs = bias[col];
#pragma unroll
            for (int r = 0; r < 4; ++r) {
                const int row = m0 + wr + m * 16 + crow0 + r;
                const float v = acc[m][n][r] + bs;
                if (STORE_BF16)
                    ((ushort_t*)C)[(size_t)row * N + col] = f2bf(v);
                else
                    ((float*)C)[(size_t)row * N + col] = v;
            }
        }
    }
}

// ---------- stage A1: RoPE + unit-normalize -> xnorm bf16 [tok*24+vec][128] ----------
// vec 0..15 = q heads, vec 16..23 = k heads. Pure register+shuffle, no LDS.
__global__ __launch_bounds__(256) void rope_norm_kernel(
    const ushort_t* __restrict__ qkv, ushort_t* __restrict__ xnorm)
{
    const int tok = blockIdx.x;
    const int s = tok & 2047;
    const int wid = threadIdx.x >> 6, lane = threadIdx.x & 63;

    // inv_freq[lane] = 10000^(-lane/64); angle = s * inv_freq
    float invf = exp2f(-(float)lane * (13.287712379549449f / 64.0f));
    float ang = (float)s * invf;
    float sn, cs;
    sincosf(ang, &sn, &cs);

    const ushort_t* row = qkv + (size_t)tok * 4096;
#pragma unroll
    for (int i = 0; i < 6; ++i) {
        int vec = wid * 6 + i;
        int base = (vec < 16) ? vec * 128 : 2048 + (vec - 16) * 128;
        float a = bf2f(row[base + lane]);        // x[d], d = lane
        float c = bf2f(row[base + lane + 64]);   // x[d+64]
        float ra = a * cs - c * sn;              // rope'd
        float rc = c * cs + a * sn;
        float ss2 = ra * ra + rc * rc;
#pragma unroll
        for (int off = 32; off; off >>= 1) ss2 += __shfl_xor(ss2, off);
        float inv = 1.0f / fmaxf(sqrtf(ss2), 1e-6f);
        ushort_t* orow = xnorm + (size_t)tok * 3072 + vec * 128;
        orow[lane]      = f2bf(ra * inv);
        orow[lane + 64] = f2bf(rc * inv);
    }
}

// ---------- stage A2: feats = [sin,cos](xnorm @ R^T)/sqrt(F), in-place ----------
// MFMA 16x16x32, fragments loaded directly from global (no LDS).
// Each wave: 32 rows x 64 feats, K=128. In-place is safe: a wave reads only
// its own 32 rows, and all loads precede all stores within the wave.
__global__ __launch_bounds__(256) void feats_kernel(
    ushort_t* __restrict__ xnorm, const ushort_t* __restrict__ Rbf)
{
    const int wid = threadIdx.x >> 6, lane = threadIdx.x & 63;
    const int r0 = blockIdx.x * 128 + wid * 32;
    const int fr = lane & 15, fk = (lane >> 4) << 3;

    bf16x8 bfv[4][4];
#pragma unroll
    for (int n = 0; n < 4; ++n)
#pragma unroll
        for (int kk = 0; kk < 4; ++kk)
            bfv[n][kk] = *reinterpret_cast<const bf16x8*>(
                Rbf + (n * 16 + fr) * 128 + kk * 32 + fk);

    f32x4 acc[2][4] = {};
#pragma unroll
    for (int m = 0; m < 2; ++m) {
#pragma unroll
        for (int kk = 0; kk < 4; ++kk) {
            bf16x8 af = *reinterpret_cast<const bf16x8*>(
                xnorm + (size_t)(r0 + m * 16 + fr) * 128 + kk * 32 + fk);
#pragma unroll
            for (int n = 0; n < 4; ++n)
                acc[m][n] = __builtin_amdgcn_mfma_f32_16x16x32_bf16(
                    af, bfv[n][kk], acc[m][n], 0, 0, 0);
        }
    }

    const int crow0 = (lane >> 4) << 2;
#pragma unroll
    for (int m = 0; m < 2; ++m)
#pragma unroll
        for (int n = 0; n < 4; ++n) {
            int e = n * 16 + fr;
#pragma unroll
            for (int r = 0; r < 4; ++r) {
                int row = r0 + m * 16 + crow0 + r;
                float p = acc[m][n][r];
                float sp, cp;
                sincosf(p, &sp, &cp);
                ushort_t* orow = xnorm + (size_t)row * 128;
                orow[e]      = f2bf(sp * 0.08838834764831845f);
                orow[e + 64] = f2bf(cp * 0.08838834764831845f);
            }
        }
}

// ---------- stage A3: per-token head contraction ----------
// A[h][hk] = <qp[h], kp[hk]>;  out[h][d] = 2 * sum_hk A[h][hk] * v[hk][d]
// LDS padded to stride 132 (conflict-free float4 reads). Scrambled ctx store
// matching the reference's transpose-free reshape.
__global__ __launch_bounds__(256) void ctx_kernel(
    const ushort_t* __restrict__ feats, const ushort_t* __restrict__ qkv,
    ushort_t* __restrict__ ctx)
{
    __shared__ float qp[16][132];
    __shared__ float kp[8][132];
    __shared__ float vsm[8][132];
    __shared__ float Apart[2][16][8];
    __shared__ float Am[16][8];

    const int tok = blockIdx.x;
    const int b = tok >> 11, s = tok & 2047;
    const int tid = threadIdx.x;
    const ushort_t* frow = feats + (size_t)tok * 3072;
    const ushort_t* vrow = qkv + (size_t)tok * 4096 + 3072;

    for (int idx = tid; idx < 3072; idx += 256) {
        int vec = idx >> 7, d = idx & 127;
        float f = bf2f(frow[idx]);
        if (vec < 16) qp[vec][d] = f; else kp[vec - 16][d] = f;
    }
    for (int idx = tid; idx < 1024; idx += 256)
        vsm[idx >> 7][idx & 127] = bf2f(vrow[idx]);
    __syncthreads();

    {   // A-dots: 256 threads = 128 (h,hk) pairs x 2 f-halves
        int half = tid >> 7, pid = tid & 127;
        int h = pid >> 3, hk = pid & 7;
        int f0 = half * 64;
        float acc = 0.f;
#pragma unroll
        for (int f = 0; f < 64; f += 4) {
            float4 qa = *reinterpret_cast<const float4*>(&qp[h][f0 + f]);
            float4 ka = *reinterpret_cast<const float4*>(&kp[hk][f0 + f]);
            acc = fmaf(qa.x, ka.x, acc); acc = fmaf(qa.y, ka.y, acc);
            acc = fmaf(qa.z, ka.z, acc); acc = fmaf(qa.w, ka.w, acc);
        }
        Apart[half][h][hk] = acc;
    }
    __syncthreads();
    if (tid < 128) {
        int h = tid >> 3, hk = tid & 7;
        Am[h][hk] = 2.0f * (Apart[0][h][hk] + Apart[1][h][hk]);
    }
    __syncthreads();

    for (int idx = tid; idx < 2048; idx += 256) {
        int h = idx >> 7, d = idx & 127;
        float acc = 0.f;
#pragma unroll
        for (int hk = 0; hk < 8; ++hk) acc = fmaf(Am[h][hk], vsm[hk][d], acc);
        int row = (b << 11) + (h << 7) + (s >> 4);
        int col = ((s & 15) << 7) + d;
        ctx[(size_t)row * 2048 + col] = f2bf(acc);
    }
}

// ---------- launch ----------
extern "C" void kernel_launch(void* const* d_in, const int* in_sizes, int n_in,
                              void* d_out, int out_size, void* d_ws, size_t ws_size,
                              hipStream_t stream)
{
    const float* hs = (const float*)d_in[0];
    const float* Wq = (const float*)d_in[1];
    const float* bq = (const float*)d_in[2];
    const float* Wk = (const float*)d_in[3];
    const float* bk = (const float*)d_in[4];
    const float* Wv = (const float*)d_in[5];
    const float* bv = (const float*)d_in[6];
    const float* Wo = (const float*)d_in[7];
    const float* bo = (const float*)d_in[8];
    const float* Rm = (const float*)d_in[9];
    float* out = (float*)d_out;

    char* ws = (char*)d_ws;
    ushort_t* Xb   = (ushort_t*)(ws);                 // 4096x2048 bf16
    ushort_t* Wcat = (ushort_t*)(ws + 16777216);      // 4096x2048 bf16 (Wq;Wk;Wv)
    ushort_t* Wo16 = (ushort_t*)(ws + 33554432);      // 2048x2048 bf16
    ushort_t* qkv  = (ushort_t*)(ws + 41943040);      // 4096x4096 bf16
    ushort_t* ctx  = (ushort_t*)(ws + 75497472);      // 4096x2048 bf16 (scrambled)
    float*    bcat = (float*)   (ws + 92274688);      // 4096 f32
    ushort_t* Rbf  = (ushort_t*)(ws + 92291072);      // 64x128 bf16
    // xnorm/feats reuses the Xb+Wcat region (free after GEMM1): 98304x128 bf16
    ushort_t* xnorm = (ushort_t*)(ws);

    // casts to bf16
    cvt_bf16_kernel<<<8192, 256, 0, stream>>>(hs, Xb, 8388608);
    cvt_bf16_kernel<<<4096, 256, 0, stream>>>(Wq, Wcat, 4194304);
    cvt_bf16_kernel<<<2048, 256, 0, stream>>>(Wk, Wcat + 4194304, 2097152);
    cvt_bf16_kernel<<<2048, 256, 0, stream>>>(Wv, Wcat + 6291456, 2097152);
    cvt_bf16_kernel<<<4096, 256, 0, stream>>>(Wo, Wo16, 4194304);
    cvt_bf16_kernel<<<8, 256, 0, stream>>>(Rm, Rbf, 8192);
    build_bcat_kernel<<<16, 256, 0, stream>>>(bq, bk, bv, bcat);

    // qkv = X @ [Wq;Wk;Wv]^T + bcat   (M=4096, N=4096, K=2048)
    gemm_bt_kernel<true><<<dim3(32, 32), 256, 0, stream>>>(
        Xb, Wcat, bcat, qkv, 4096, 4096, 2048);

    // attention stage, token-parallel
    rope_norm_kernel<<<4096, 256, 0, stream>>>(qkv, xnorm);
    feats_kernel<<<768, 256, 0, stream>>>(xnorm, Rbf);
    ctx_kernel<<<4096, 256, 0, stream>>>(xnorm, qkv, ctx);

    // out = ctx @ Wo^T + bo   (M=4096, N=2048, K=2048), fp32 out
    gemm_bt_kernel<false><<<dim3(16, 32), 256, 0, stream>>>(
        ctx, Wo16, bo, out, 4096, 2048, 2048);
}

// Round 3
// 186.048 us; speedup vs baseline: 1.9284x; 1.2820x over previous
//
#include <hip/hip_runtime.h>
#include <stdint.h>

typedef unsigned short ushort_t;
typedef __bf16 bf16x8 __attribute__((ext_vector_type(8)));
typedef float f32x4 __attribute__((ext_vector_type(4)));
typedef unsigned int u32;

// ---------- bf16 helpers (manual, RNE) ----------
__device__ __forceinline__ float bf2f(ushort_t u) {
    union { u32 u; float f; } x; x.u = ((u32)u) << 16; return x.f;
}
__device__ __forceinline__ ushort_t f2bf(float f) {
    union { float f; u32 u; } x; x.f = f;
    u32 r = x.u + 0x7FFFu + ((x.u >> 16) & 1u);
    return (ushort_t)(r >> 16);
}

// ---------- async global->LDS, 16B per lane ----------
__device__ __forceinline__ void async16(const void* gp, void* lp) {
    __builtin_amdgcn_global_load_lds(
        (const __attribute__((address_space(1))) u32*)(gp),
        (__attribute__((address_space(3))) u32*)(lp),
        16, 0, 0);
}

template<int N>
__device__ __forceinline__ void wait_barrier() {
    asm volatile("s_waitcnt vmcnt(%0)\n\ts_barrier" :: "n"(N) : "memory");
}

// ---------- fp32 -> bf16 cast (vectorized) ----------
__global__ __launch_bounds__(256) void cvt_bf16_kernel(
    const float* __restrict__ in, ushort_t* __restrict__ out, int n)
{
    int i = (blockIdx.x * 256 + threadIdx.x) * 4;
    if (i >= n) return;
    float4 v = *reinterpret_cast<const float4*>(in + i);
    ushort4 o;
    o.x = f2bf(v.x); o.y = f2bf(v.y); o.z = f2bf(v.z); o.w = f2bf(v.w);
    *reinterpret_cast<ushort4*>(out + i) = o;
}

// ---------- concatenated qkv bias ----------
__global__ void build_bcat_kernel(const float* __restrict__ bq,
                                  const float* __restrict__ bk,
                                  const float* __restrict__ bv,
                                  float* __restrict__ bcat)
{
    int i = blockIdx.x * 256 + threadIdx.x;   // 0..4095
    float v = (i < 2048) ? bq[i] : (i < 3072) ? bk[i - 2048] : bv[i - 3072];
    bcat[i] = v;
}

// ---------- pipelined bf16 GEMM:  C[M,N] = A[M,K] @ B[N,K]^T + bias ----------
// BM x 256 tile, BK=32, 512 threads = 8 waves (2M x 4N), per-wave (BM/2) x 64.
// 4-deep LDS ring, counted vmcnt (never 0 in main loop), chunk-XOR swizzle
// (T2: conflict-free ds_read_b128), setprio around MFMA (T5), XCD rect (T1).
// Requires: M%BM==0, N%256==0, K%32==0, grid == (M/BM)*(N/256) == 256 blocks,
// (M/BM)%4==0, (N/256)%8==0.
template<int BM, bool STORE_BF16>
__global__ __launch_bounds__(512, 2) void gemm_pipe_kernel(
    const ushort_t* __restrict__ A, const ushort_t* __restrict__ B,
    const float* __restrict__ bias, void* __restrict__ C,
    const int M, const int N, const int K)
{
    constexpr int MFRAG = BM / 32;        // 16-row frags per wave (m dim)
    constexpr int ISS_A = BM / 128;       // global_load_lds issues per tile (A)
    constexpr int ISS   = ISS_A + 2;      // total issues per tile per thread
    constexpr int ABYT  = BM * 64;        // A-tile bytes (BM rows x 64B)
    constexpr int AW    = BM * 32;        // per-wave-panel A bytes ((BM/2)*64)
    constexpr int BUFB  = ABYT + 16384;   // ring buffer stride
    __shared__ alignas(16) char lds[4 * BUFB];

    const int tid  = threadIdx.x;
    const int wid  = tid >> 6;
    const int lane = tid & 63;
    const int wm = wid >> 2, wn = wid & 3;

    // T1: XCD rect mapping. XCD x = blockIdx%8 gets a 4(m) x 8(n) rect.
    const int NBM = M / BM;
    const int RX  = NBM >> 2;             // rects along m
    const int x  = blockIdx.x & 7;
    const int kk = blockIdx.x >> 3;       // 0..31
    const int mb = (x % RX) * 4 + (kk >> 3);
    const int nb = (x / RX) * 8 + (kk & 7);
    const int am0 = mb * BM, bn0 = nb * 256;
    const int NT = K >> 5;

    // staging constants: thread covers row sr (per 128-row issue), 16B chunk.
    // T2 write side: linear LDS dest, pre-swizzled global source chunk.
    const int sr  = tid >> 2;
    const int scb = (tid & 3) ^ ((sr >> 1) & 3);
    const size_t argb = (size_t)(am0 + sr) * K + scb * 8;
    const size_t brgb = (size_t)(bn0 + sr) * K + scb * 8;
    const int ldswave = wid << 10;        // wave-uniform LDS byte base per issue

    // frag-read constants. T2 read side: same XOR on the 16B chunk index.
    const int fr = lane & 15;
    const int fc = lane >> 4;
    const int rswz  = (fc ^ ((fr >> 1) & 3)) << 4;
    const int aoff0 = wm * AW + fr * 64 + rswz;
    const int boff0 = ABYT + wn * 4096 + fr * 64 + rswz;

    f32x4 acc[MFRAG][4] = {};

    auto stage = [&](int t) {
        char* lp = lds + (t & 3) * BUFB;
        const size_t kof = (size_t)t << 5;
#pragma unroll
        for (int i = 0; i < ISS_A; ++i)
            async16(A + argb + (size_t)(i * 128) * K + kof,
                    lp + i * 8192 + ldswave);
#pragma unroll
        for (int i = 0; i < 2; ++i)
            async16(B + brgb + (size_t)(i * 128) * K + kof,
                    lp + ABYT + i * 8192 + ldswave);
    };

    auto compute = [&](int t) {
        const char* lp = lds + (t & 3) * BUFB;
        bf16x8 af[MFRAG], bfr[4];
#pragma unroll
        for (int n = 0; n < 4; ++n)
            bfr[n] = *(const bf16x8*)(lp + boff0 + n * 1024);
#pragma unroll
        for (int m = 0; m < MFRAG; ++m)
            af[m] = *(const bf16x8*)(lp + aoff0 + m * 1024);
        __builtin_amdgcn_s_setprio(1);
#pragma unroll
        for (int m = 0; m < MFRAG; ++m)
#pragma unroll
            for (int n = 0; n < 4; ++n)
                acc[m][n] = __builtin_amdgcn_mfma_f32_16x16x32_bf16(
                    af[m], bfr[n], acc[m][n], 0, 0, 0);
        __builtin_amdgcn_s_setprio(0);
        // ensure all this iter's ds_reads are serviced before our next barrier
        // (closes the queued-read vs incoming-staging race; ~free: already
        // drained by the compiler's pre-MFMA lgkm waits).
        asm volatile("s_waitcnt lgkmcnt(0)" ::: "memory");
    };

    // prologue: 3 tiles in flight
    stage(0); stage(1); stage(2);

    for (int t = 0; t < NT - 2; ++t) {
        wait_barrier<2 * ISS>();          // tile t resident; t+1,t+2 in flight
        if (t + 3 < NT) stage(t + 3);     // overwrites buffer last read at t-1
        compute(t);
    }
    wait_barrier<ISS>(); compute(NT - 2);
    wait_barrier<0>();   compute(NT - 1);

    // epilogue: C/D layout col = lane&15, row = (lane>>4)*4 + reg
    const int crow0 = fc << 2;
#pragma unroll
    for (int m = 0; m < MFRAG; ++m) {
        const int row_b = am0 + wm * (BM / 2) + m * 16 + crow0;
#pragma unroll
        for (int n = 0; n < 4; ++n) {
            const int col = bn0 + wn * 64 + n * 16 + fr;
            const float bs = bias[col];
#pragma unroll
            for (int r = 0; r < 4; ++r) {
                const float v = acc[m][n][r] + bs;
                if (STORE_BF16)
                    ((ushort_t*)C)[(size_t)(row_b + r) * N + col] = f2bf(v);
                else
                    ((float*)C)[(size_t)(row_b + r) * N + col] = v;
            }
        }
    }
}

// ---------- stage A1: RoPE + unit-normalize -> xnorm bf16 [tok*24+vec][128] ----------
__global__ __launch_bounds__(256) void rope_norm_kernel(
    const ushort_t* __restrict__ qkv, ushort_t* __restrict__ xnorm)
{
    const int tok = blockIdx.x;
    const int s = tok & 2047;
    const int wid = threadIdx.x >> 6, lane = threadIdx.x & 63;

    float invf = exp2f(-(float)lane * (13.287712379549449f / 64.0f));
    float ang = (float)s * invf;
    float sn, cs;
    sincosf(ang, &sn, &cs);

    const ushort_t* row = qkv + (size_t)tok * 4096;
#pragma unroll
    for (int i = 0; i < 6; ++i) {
        int vec = wid * 6 + i;
        int base = (vec < 16) ? vec * 128 : 2048 + (vec - 16) * 128;
        float a = bf2f(row[base + lane]);
        float c = bf2f(row[base + lane + 64]);
        float ra = a * cs - c * sn;
        float rc = c * cs + a * sn;
        float ss2 = ra * ra + rc * rc;
#pragma unroll
        for (int off = 32; off; off >>= 1) ss2 += __shfl_xor(ss2, off);
        float inv = 1.0f / fmaxf(sqrtf(ss2), 1e-6f);
        ushort_t* orow = xnorm + (size_t)tok * 3072 + vec * 128;
        orow[lane]      = f2bf(ra * inv);
        orow[lane + 64] = f2bf(rc * inv);
    }
}

// ---------- stage A2: feats = [sin,cos](xnorm @ R^T)/sqrt(F), in-place ----------
__global__ __launch_bounds__(256) void feats_kernel(
    ushort_t* __restrict__ xnorm, const ushort_t* __restrict__ Rbf)
{
    const int wid = threadIdx.x >> 6, lane = threadIdx.x & 63;
    const int r0 = blockIdx.x * 128 + wid * 32;
    const int fr = lane & 15, fk = (lane >> 4) << 3;

    bf16x8 bfv[4][4];
#pragma unroll
    for (int n = 0; n < 4; ++n)
#pragma unroll
        for (int kk = 0; kk < 4; ++kk)
            bfv[n][kk] = *reinterpret_cast<const bf16x8*>(
                Rbf + (n * 16 + fr) * 128 + kk * 32 + fk);

    f32x4 acc[2][4] = {};
#pragma unroll
    for (int m = 0; m < 2; ++m) {
#pragma unroll
        for (int kk = 0; kk < 4; ++kk) {
            bf16x8 af = *reinterpret_cast<const bf16x8*>(
                xnorm + (size_t)(r0 + m * 16 + fr) * 128 + kk * 32 + fk);
#pragma unroll
            for (int n = 0; n < 4; ++n)
                acc[m][n] = __builtin_amdgcn_mfma_f32_16x16x32_bf16(
                    af, bfv[n][kk], acc[m][n], 0, 0, 0);
        }
    }

    const int crow0 = (lane >> 4) << 2;
#pragma unroll
    for (int m = 0; m < 2; ++m)
#pragma unroll
        for (int n = 0; n < 4; ++n) {
            int e = n * 16 + fr;
#pragma unroll
            for (int r = 0; r < 4; ++r) {
                int row = r0 + m * 16 + crow0 + r;
                float p = acc[m][n][r];
                float sp, cp;
                sincosf(p, &sp, &cp);
                ushort_t* orow = xnorm + (size_t)row * 128;
                orow[e]      = f2bf(sp * 0.08838834764831845f);
                orow[e + 64] = f2bf(cp * 0.08838834764831845f);
            }
        }
}

// ---------- stage A3: per-token head contraction ----------
__global__ __launch_bounds__(256) void ctx_kernel(
    const ushort_t* __restrict__ feats, const ushort_t* __restrict__ qkv,
    ushort_t* __restrict__ ctx)
{
    __shared__ float qp[16][132];
    __shared__ float kp[8][132];
    __shared__ float vsm[8][132];
    __shared__ float Apart[2][16][8];
    __shared__ float Am[16][8];

    const int tok = blockIdx.x;
    const int b = tok >> 11, s = tok & 2047;
    const int tid = threadIdx.x;
    const ushort_t* frow = feats + (size_t)tok * 3072;
    const ushort_t* vrow = qkv + (size_t)tok * 4096 + 3072;

    for (int idx = tid; idx < 3072; idx += 256) {
        int vec = idx >> 7, d = idx & 127;
        float f = bf2f(frow[idx]);
        if (vec < 16) qp[vec][d] = f; else kp[vec - 16][d] = f;
    }
    for (int idx = tid; idx < 1024; idx += 256)
        vsm[idx >> 7][idx & 127] = bf2f(vrow[idx]);
    __syncthreads();

    {
        int half = tid >> 7, pid = tid & 127;
        int h = pid >> 3, hk = pid & 7;
        int f0 = half * 64;
        float acc = 0.f;
#pragma unroll
        for (int f = 0; f < 64; f += 4) {
            float4 qa = *reinterpret_cast<const float4*>(&qp[h][f0 + f]);
            float4 ka = *reinterpret_cast<const float4*>(&kp[hk][f0 + f]);
            acc = fmaf(qa.x, ka.x, acc); acc = fmaf(qa.y, ka.y, acc);
            acc = fmaf(qa.z, ka.z, acc); acc = fmaf(qa.w, ka.w, acc);
        }
        Apart[half][h][hk] = acc;
    }
    __syncthreads();
    if (tid < 128) {
        int h = tid >> 3, hk = tid & 7;
        Am[h][hk] = 2.0f * (Apart[0][h][hk] + Apart[1][h][hk]);
    }
    __syncthreads();

    for (int idx = tid; idx < 2048; idx += 256) {
        int h = idx >> 7, d = idx & 127;
        float acc = 0.f;
#pragma unroll
        for (int hk = 0; hk < 8; ++hk) acc = fmaf(Am[h][hk], vsm[hk][d], acc);
        int row = (b << 11) + (h << 7) + (s >> 4);
        int col = ((s & 15) << 7) + d;
        ctx[(size_t)row * 2048 + col] = f2bf(acc);
    }
}

// ---------- launch ----------
extern "C" void kernel_launch(void* const* d_in, const int* in_sizes, int n_in,
                              void* d_out, int out_size, void* d_ws, size_t ws_size,
                              hipStream_t stream)
{
    const float* hs = (const float*)d_in[0];
    const float* Wq = (const float*)d_in[1];
    const float* bq = (const float*)d_in[2];
    const float* Wk = (const float*)d_in[3];
    const float* bk = (const float*)d_in[4];
    const float* Wv = (const float*)d_in[5];
    const float* bv = (const float*)d_in[6];
    const float* Wo = (const float*)d_in[7];
    const float* bo = (const float*)d_in[8];
    const float* Rm = (const float*)d_in[9];
    float* out = (float*)d_out;

    char* ws = (char*)d_ws;
    ushort_t* Xb   = (ushort_t*)(ws);                 // 4096x2048 bf16
    ushort_t* Wcat = (ushort_t*)(ws + 16777216);      // 4096x2048 bf16 (Wq;Wk;Wv)
    ushort_t* Wo16 = (ushort_t*)(ws + 33554432);      // 2048x2048 bf16
    ushort_t* qkv  = (ushort_t*)(ws + 41943040);      // 4096x4096 bf16
    ushort_t* ctx  = (ushort_t*)(ws + 75497472);      // 4096x2048 bf16 (scrambled)
    float*    bcat = (float*)   (ws + 92274688);      // 4096 f32
    ushort_t* Rbf  = (ushort_t*)(ws + 92291072);      // 64x128 bf16
    ushort_t* xnorm = (ushort_t*)(ws);                // reuses Xb+Wcat region

    cvt_bf16_kernel<<<8192, 256, 0, stream>>>(hs, Xb, 8388608);
    cvt_bf16_kernel<<<4096, 256, 0, stream>>>(Wq, Wcat, 4194304);
    cvt_bf16_kernel<<<2048, 256, 0, stream>>>(Wk, Wcat + 4194304, 2097152);
    cvt_bf16_kernel<<<2048, 256, 0, stream>>>(Wv, Wcat + 6291456, 2097152);
    cvt_bf16_kernel<<<4096, 256, 0, stream>>>(Wo, Wo16, 4194304);
    cvt_bf16_kernel<<<8, 256, 0, stream>>>(Rm, Rbf, 8192);
    build_bcat_kernel<<<16, 256, 0, stream>>>(bq, bk, bv, bcat);

    // qkv = X @ [Wq;Wk;Wv]^T + bcat   (M=4096, N=4096, K=2048)
    gemm_pipe_kernel<256, true><<<256, 512, 0, stream>>>(
        Xb, Wcat, bcat, qkv, 4096, 4096, 2048);

    rope_norm_kernel<<<4096, 256, 0, stream>>>(qkv, xnorm);
    feats_kernel<<<768, 256, 0, stream>>>(xnorm, Rbf);
    ctx_kernel<<<4096, 256, 0, stream>>>(xnorm, qkv, ctx);

    // out = ctx @ Wo^T + bo   (M=4096, N=2048, K=2048), fp32 out
    gemm_pipe_kernel<128, false><<<256, 512, 0, stream>>>(
        ctx, Wo16, bo, out, 4096, 2048, 2048);
}

// Round 4
// 175.802 us; speedup vs baseline: 2.0408x; 1.0583x over previous
//
#include <hip/hip_runtime.h>
#include <stdint.h>

typedef unsigned short ushort_t;
typedef __bf16 bf16x8 __attribute__((ext_vector_type(8)));
typedef float f32x4 __attribute__((ext_vector_type(4)));
typedef unsigned int u32;

// ---------- bf16 helpers (manual, RNE) ----------
__device__ __forceinline__ float bf2f(ushort_t u) {
    union { u32 u; float f; } x; x.u = ((u32)u) << 16; return x.f;
}
__device__ __forceinline__ ushort_t f2bf(float f) {
    union { float f; u32 u; } x; x.f = f;
    u32 r = x.u + 0x7FFFu + ((x.u >> 16) & 1u);
    return (ushort_t)(r >> 16);
}

// ---------- async global->LDS, 16B per lane ----------
__device__ __forceinline__ void async16(const void* gp, void* lp) {
    __builtin_amdgcn_global_load_lds(
        (const __attribute__((address_space(1))) u32*)(gp),
        (__attribute__((address_space(3))) u32*)(lp),
        16, 0, 0);
}

template<int N>
__device__ __forceinline__ void wait_barrier() {
    asm volatile("s_waitcnt vmcnt(%0)\n\ts_barrier" :: "n"(N) : "memory");
}

// ---------- fused fp32 -> bf16 casts (one launch for all inputs) ----------
// block ranges: hs[0,8192) Wq[8192,12288) Wk[12288,14336) Wv[14336,16384)
// Wo[16384,20480) R[20480,20488); each block converts 1024 floats.
__global__ __launch_bounds__(256) void cast_all_kernel(
    const float* __restrict__ hs, const float* __restrict__ Wq,
    const float* __restrict__ Wk, const float* __restrict__ Wv,
    const float* __restrict__ Wo, const float* __restrict__ Rm,
    ushort_t* __restrict__ Xb, ushort_t* __restrict__ Wcat,
    ushort_t* __restrict__ Wo16, ushort_t* __restrict__ Rbf)
{
    int bid = blockIdx.x;
    const float* src; ushort_t* dst; int base;
    if (bid < 8192)       { src = hs; dst = Xb;              base = bid; }
    else if (bid < 12288) { src = Wq; dst = Wcat;            base = bid - 8192; }
    else if (bid < 14336) { src = Wk; dst = Wcat + 4194304;  base = bid - 12288; }
    else if (bid < 16384) { src = Wv; dst = Wcat + 6291456;  base = bid - 14336; }
    else if (bid < 20480) { src = Wo; dst = Wo16;            base = bid - 16384; }
    else                  { src = Rm; dst = Rbf;             base = bid - 20480; }
    int i = (base * 256 + threadIdx.x) * 4;
    float4 v = *reinterpret_cast<const float4*>(src + i);
    ushort4 o;
    o.x = f2bf(v.x); o.y = f2bf(v.y); o.z = f2bf(v.z); o.w = f2bf(v.w);
    *reinterpret_cast<ushort4*>(dst + i) = o;
}

// ---------- concatenated qkv bias ----------
__global__ void build_bcat_kernel(const float* __restrict__ bq,
                                  const float* __restrict__ bk,
                                  const float* __restrict__ bv,
                                  float* __restrict__ bcat)
{
    int i = blockIdx.x * 256 + threadIdx.x;   // 0..4095
    float v = (i < 2048) ? bq[i] : (i < 3072) ? bk[i - 2048] : bv[i - 3072];
    bcat[i] = v;
}

// ---------- pipelined bf16 GEMM:  C[M,N] = A[M,K] @ B[N,K]^T + bias ----------
// BM x 256 tile, BK=32, 512 threads = 8 waves (2M x 4N), per-wave (BM/2) x 64.
// 4-deep LDS ring + REGISTER double-buffer: at tile t, ds_read frags(t+1)
// (LDS-resident: 3-tile prefetch), MFMA on frags(t) read last iter. Counted
// vmcnt (never 0 until epilogue), chunk-XOR swizzle (0 bank conflicts, R3),
// setprio around MFMA, XCD rect mapping. Trailing lgkmcnt(0) fences each
// iter's ds_reads before the wave's next barrier (overwrite-race fence).
template<int BM, int KC, bool STORE_BF16>
__global__ __launch_bounds__(512, 2) void gemm_pipe_kernel(
    const ushort_t* __restrict__ A, const ushort_t* __restrict__ B,
    const float* __restrict__ bias, void* __restrict__ C,
    const int M, const int N)
{
    constexpr int MFRAG = BM / 32;
    constexpr int ISS_A = BM / 128;
    constexpr int ISS   = ISS_A + 2;      // global_load_lds per thread per tile
    constexpr int ABYT  = BM * 64;
    constexpr int AW    = BM * 32;
    constexpr int BUFB  = ABYT + 16384;
    constexpr int NT    = KC >> 5;
    static_assert(NT >= 6 && (NT & 1) == 0, "tail peel needs even NT>=6");
    __shared__ alignas(16) char lds[4 * BUFB];

    const int tid  = threadIdx.x;
    const int wid  = tid >> 6;
    const int lane = tid & 63;
    const int wm = wid >> 2, wn = wid & 3;

    // T1: XCD rect mapping (exact: 256 blocks, 8 XCDs, 4x8 rects)
    const int NBM = M / BM;
    const int RX  = NBM >> 2;
    const int x  = blockIdx.x & 7;
    const int kk = blockIdx.x >> 3;
    const int mb = (x % RX) * 4 + (kk >> 3);
    const int nb = (x / RX) * 8 + (kk & 7);
    const int am0 = mb * BM, bn0 = nb * 256;

    // staging: thread covers row sr per 128-row issue, swizzled source chunk
    const int sr  = tid >> 2;
    const int scb = (tid & 3) ^ ((sr >> 1) & 3);
    const size_t argb = (size_t)(am0 + sr) * KC + scb * 8;
    const size_t brgb = (size_t)(bn0 + sr) * KC + scb * 8;
    const int ldswave = wid << 10;

    // frag-read constants (swizzled chunk)
    const int fr = lane & 15;
    const int fc = lane >> 4;
    const int rswz  = (fc ^ ((fr >> 1) & 3)) << 4;
    const int aoff0 = wm * AW + fr * 64 + rswz;
    const int boff0 = ABYT + wn * 4096 + fr * 64 + rswz;

    f32x4 acc[MFRAG][4] = {};
    bf16x8 afA[MFRAG], bfA[4], afB[MFRAG], bfB[4];

    auto stage = [&](int t) {
        char* lp = lds + (t & 3) * BUFB;
        const size_t kof = (size_t)t << 5;
#pragma unroll
        for (int i = 0; i < ISS_A; ++i)
            async16(A + argb + (size_t)(i * 128) * KC + kof,
                    lp + i * 8192 + ldswave);
#pragma unroll
        for (int i = 0; i < 2; ++i)
            async16(B + brgb + (size_t)(i * 128) * KC + kof,
                    lp + ABYT + i * 8192 + ldswave);
    };

    auto ldfrags = [&](int t, bf16x8 (&af)[MFRAG], bf16x8 (&bf)[4]) {
        const char* lp = lds + (t & 3) * BUFB;
#pragma unroll
        for (int n = 0; n < 4; ++n)
            bf[n] = *(const bf16x8*)(lp + boff0 + n * 1024);
#pragma unroll
        for (int m = 0; m < MFRAG; ++m)
            af[m] = *(const bf16x8*)(lp + aoff0 + m * 1024);
    };

    auto domfma = [&](bf16x8 (&af)[MFRAG], bf16x8 (&bf)[4]) {
        __builtin_amdgcn_s_setprio(1);
#pragma unroll
        for (int m = 0; m < MFRAG; ++m)
#pragma unroll
            for (int n = 0; n < 4; ++n)
                acc[m][n] = __builtin_amdgcn_mfma_f32_16x16x32_bf16(
                    af[m], bf[n], acc[m][n], 0, 0, 0);
        __builtin_amdgcn_s_setprio(0);
        // fence: this iter's ds_reads must drain before our next barrier
        asm volatile("s_waitcnt lgkmcnt(0)" ::: "memory");
    };

    // prologue: 3 tiles in flight; tile 0 resident -> frags(0) in regs
    stage(0); stage(1); stage(2);
    wait_barrier<2 * ISS>();
    ldfrags(0, afA, bfA);

    // main loop: pair-unrolled (compile-time regset swap, rule 20)
    for (int t = 0; t < NT - 4; t += 2) {
        stage(t + 3);
        wait_barrier<2 * ISS>();          // tile t+1 resident; t+2,t+3 in flight
        ldfrags(t + 1, afB, bfB);
        domfma(afA, bfA);                 // tile t
        stage(t + 4);
        wait_barrier<2 * ISS>();
        ldfrags(t + 2, afA, bfA);
        domfma(afB, bfB);                 // tile t+1
    }
    // tail: tiles NT-4 .. NT-1
    stage(NT - 1);
    wait_barrier<2 * ISS>();
    ldfrags(NT - 3, afB, bfB);
    domfma(afA, bfA);                     // NT-4
    wait_barrier<ISS>();
    ldfrags(NT - 2, afA, bfA);
    domfma(afB, bfB);                     // NT-3
    wait_barrier<0>();
    ldfrags(NT - 1, afB, bfB);
    domfma(afA, bfA);                     // NT-2
    domfma(afB, bfB);                     // NT-1

    // epilogue: C/D layout col = lane&15, row = (lane>>4)*4 + reg
    const int crow0 = fc << 2;
#pragma unroll
    for (int m = 0; m < MFRAG; ++m) {
        const int row_b = am0 + wm * (BM / 2) + m * 16 + crow0;
#pragma unroll
        for (int n = 0; n < 4; ++n) {
            const int col = bn0 + wn * 64 + n * 16 + fr;
            const float bs = bias[col];
#pragma unroll
            for (int r = 0; r < 4; ++r) {
                const float v = acc[m][n][r] + bs;
                if (STORE_BF16)
                    ((ushort_t*)C)[(size_t)(row_b + r) * N + col] = f2bf(v);
                else
                    ((float*)C)[(size_t)(row_b + r) * N + col] = v;
            }
        }
    }
}

// ---------- stage A1: RoPE + unit-normalize -> xnorm bf16 [tok*24+vec][128] ----------
__global__ __launch_bounds__(256) void rope_norm_kernel(
    const ushort_t* __restrict__ qkv, ushort_t* __restrict__ xnorm)
{
    const int tok = blockIdx.x;
    const int s = tok & 2047;
    const int wid = threadIdx.x >> 6, lane = threadIdx.x & 63;

    float invf = exp2f(-(float)lane * (13.287712379549449f / 64.0f));
    float ang = (float)s * invf;
    float sn, cs;
    sincosf(ang, &sn, &cs);

    const ushort_t* row = qkv + (size_t)tok * 4096;
#pragma unroll
    for (int i = 0; i < 6; ++i) {
        int vec = wid * 6 + i;
        int base = (vec < 16) ? vec * 128 : 2048 + (vec - 16) * 128;
        float a = bf2f(row[base + lane]);
        float c = bf2f(row[base + lane + 64]);
        float ra = a * cs - c * sn;
        float rc = c * cs + a * sn;
        float ss2 = ra * ra + rc * rc;
#pragma unroll
        for (int off = 32; off; off >>= 1) ss2 += __shfl_xor(ss2, off);
        float inv = 1.0f / fmaxf(sqrtf(ss2), 1e-6f);
        ushort_t* orow = xnorm + (size_t)tok * 3072 + vec * 128;
        orow[lane]      = f2bf(ra * inv);
        orow[lane + 64] = f2bf(rc * inv);
    }
}

// ---------- stage A2: feats = [sin,cos](xnorm @ R^T)/sqrt(F), in-place ----------
__global__ __launch_bounds__(256) void feats_kernel(
    ushort_t* __restrict__ xnorm, const ushort_t* __restrict__ Rbf)
{
    const int wid = threadIdx.x >> 6, lane = threadIdx.x & 63;
    const int r0 = blockIdx.x * 128 + wid * 32;
    const int fr = lane & 15, fk = (lane >> 4) << 3;

    bf16x8 bfv[4][4];
#pragma unroll
    for (int n = 0; n < 4; ++n)
#pragma unroll
        for (int kk = 0; kk < 4; ++kk)
            bfv[n][kk] = *reinterpret_cast<const bf16x8*>(
                Rbf + (n * 16 + fr) * 128 + kk * 32 + fk);

    f32x4 acc[2][4] = {};
#pragma unroll
    for (int m = 0; m < 2; ++m) {
#pragma unroll
        for (int kk = 0; kk < 4; ++kk) {
            bf16x8 af = *reinterpret_cast<const bf16x8*>(
                xnorm + (size_t)(r0 + m * 16 + fr) * 128 + kk * 32 + fk);
#pragma unroll
            for (int n = 0; n < 4; ++n)
                acc[m][n] = __builtin_amdgcn_mfma_f32_16x16x32_bf16(
                    af, bfv[n][kk], acc[m][n], 0, 0, 0);
        }
    }

    const int crow0 = (lane >> 4) << 2;
#pragma unroll
    for (int m = 0; m < 2; ++m)
#pragma unroll
        for (int n = 0; n < 4; ++n) {
            int e = n * 16 + fr;
#pragma unroll
            for (int r = 0; r < 4; ++r) {
                int row = r0 + m * 16 + crow0 + r;
                float p = acc[m][n][r];
                float sp, cp;
                sincosf(p, &sp, &cp);
                ushort_t* orow = xnorm + (size_t)row * 128;
                orow[e]      = f2bf(sp * 0.08838834764831845f);
                orow[e + 64] = f2bf(cp * 0.08838834764831845f);
            }
        }
}

// ---------- stage A3: per-token head contraction ----------
__global__ __launch_bounds__(256) void ctx_kernel(
    const ushort_t* __restrict__ feats, const ushort_t* __restrict__ qkv,
    ushort_t* __restrict__ ctx)
{
    __shared__ float qp[16][132];
    __shared__ float kp[8][132];
    __shared__ float vsm[8][132];
    __shared__ float Apart[2][16][8];
    __shared__ float Am[16][8];

    const int tok = blockIdx.x;
    const int b = tok >> 11, s = tok & 2047;
    const int tid = threadIdx.x;
    const ushort_t* frow = feats + (size_t)tok * 3072;
    const ushort_t* vrow = qkv + (size_t)tok * 4096 + 3072;

    for (int idx = tid; idx < 3072; idx += 256) {
        int vec = idx >> 7, d = idx & 127;
        float f = bf2f(frow[idx]);
        if (vec < 16) qp[vec][d] = f; else kp[vec - 16][d] = f;
    }
    for (int idx = tid; idx < 1024; idx += 256)
        vsm[idx >> 7][idx & 127] = bf2f(vrow[idx]);
    __syncthreads();

    {
        int half = tid >> 7, pid = tid & 127;
        int h = pid >> 3, hk = pid & 7;
        int f0 = half * 64;
        float acc = 0.f;
#pragma unroll
        for (int f = 0; f < 64; f += 4) {
            float4 qa = *reinterpret_cast<const float4*>(&qp[h][f0 + f]);
            float4 ka = *reinterpret_cast<const float4*>(&kp[hk][f0 + f]);
            acc = fmaf(qa.x, ka.x, acc); acc = fmaf(qa.y, ka.y, acc);
            acc = fmaf(qa.z, ka.z, acc); acc = fmaf(qa.w, ka.w, acc);
        }
        Apart[half][h][hk] = acc;
    }
    __syncthreads();
    if (tid < 128) {
        int h = tid >> 3, hk = tid & 7;
        Am[h][hk] = 2.0f * (Apart[0][h][hk] + Apart[1][h][hk]);
    }
    __syncthreads();

    for (int idx = tid; idx < 2048; idx += 256) {
        int h = idx >> 7, d = idx & 127;
        float acc = 0.f;
#pragma unroll
        for (int hk = 0; hk < 8; ++hk) acc = fmaf(Am[h][hk], vsm[hk][d], acc);
        int row = (b << 11) + (h << 7) + (s >> 4);
        int col = ((s & 15) << 7) + d;
        ctx[(size_t)row * 2048 + col] = f2bf(acc);
    }
}

// ---------- launch ----------
extern "C" void kernel_launch(void* const* d_in, const int* in_sizes, int n_in,
                              void* d_out, int out_size, void* d_ws, size_t ws_size,
                              hipStream_t stream)
{
    const float* hs = (const float*)d_in[0];
    const float* Wq = (const float*)d_in[1];
    const float* bq = (const float*)d_in[2];
    const float* Wk = (const float*)d_in[3];
    const float* bk = (const float*)d_in[4];
    const float* Wv = (const float*)d_in[5];
    const float* bv = (const float*)d_in[6];
    const float* Wo = (const float*)d_in[7];
    const float* bo = (const float*)d_in[8];
    const float* Rm = (const float*)d_in[9];
    float* out = (float*)d_out;

    char* ws = (char*)d_ws;
    ushort_t* Xb   = (ushort_t*)(ws);                 // 4096x2048 bf16
    ushort_t* Wcat = (ushort_t*)(ws + 16777216);      // 4096x2048 bf16 (Wq;Wk;Wv)
    ushort_t* Wo16 = (ushort_t*)(ws + 33554432);      // 2048x2048 bf16
    ushort_t* qkv  = (ushort_t*)(ws + 41943040);      // 4096x4096 bf16
    ushort_t* ctx  = (ushort_t*)(ws + 75497472);      // 4096x2048 bf16 (scrambled)
    float*    bcat = (float*)   (ws + 92274688);      // 4096 f32
    ushort_t* Rbf  = (ushort_t*)(ws + 92291072);      // 64x128 bf16
    ushort_t* xnorm = (ushort_t*)(ws);                // reuses Xb+Wcat region

    cast_all_kernel<<<20488, 256, 0, stream>>>(hs, Wq, Wk, Wv, Wo, Rm,
                                               Xb, Wcat, Wo16, Rbf);
    build_bcat_kernel<<<16, 256, 0, stream>>>(bq, bk, bv, bcat);

    // qkv = X @ [Wq;Wk;Wv]^T + bcat   (M=4096, N=4096, K=2048)
    gemm_pipe_kernel<256, 2048, true><<<256, 512, 0, stream>>>(
        Xb, Wcat, bcat, qkv, 4096, 4096);

    rope_norm_kernel<<<4096, 256, 0, stream>>>(qkv, xnorm);
    feats_kernel<<<768, 256, 0, stream>>>(xnorm, Rbf);
    ctx_kernel<<<4096, 256, 0, stream>>>(xnorm, qkv, ctx);

    // out = ctx @ Wo^T + bo   (M=4096, N=2048, K=2048), fp32 out
    gemm_pipe_kernel<128, 2048, false><<<256, 512, 0, stream>>>(
        ctx, Wo16, bo, out, 4096, 2048);
}

// Round 5
// 174.307 us; speedup vs baseline: 2.0583x; 1.0086x over previous
//
#include <hip/hip_runtime.h>
#include <stdint.h>

typedef unsigned short ushort_t;
typedef __bf16 bf16x8 __attribute__((ext_vector_type(8)));
typedef float f32x4 __attribute__((ext_vector_type(4)));
typedef unsigned int u32;

// ---------- bf16 helpers (manual, RNE) ----------
__device__ __forceinline__ float bf2f(ushort_t u) {
    union { u32 u; float f; } x; x.u = ((u32)u) << 16; return x.f;
}
__device__ __forceinline__ ushort_t f2bf(float f) {
    union { float f; u32 u; } x; x.f = f;
    u32 r = x.u + 0x7FFFu + ((x.u >> 16) & 1u);
    return (ushort_t)(r >> 16);
}

// ---------- async global->LDS, 16B per lane ----------
__device__ __forceinline__ void async16(const void* gp, void* lp) {
    __builtin_amdgcn_global_load_lds(
        (const __attribute__((address_space(1))) u32*)(gp),
        (__attribute__((address_space(3))) u32*)(lp),
        16, 0, 0);
}

template<int N>
__device__ __forceinline__ void wait_barrier() {
    asm volatile("s_waitcnt vmcnt(%0)\n\ts_barrier" :: "n"(N) : "memory");
}

// ---------- fused fp32 -> bf16 casts ----------
__global__ __launch_bounds__(256) void cast_all_kernel(
    const float* __restrict__ hs, const float* __restrict__ Wq,
    const float* __restrict__ Wk, const float* __restrict__ Wv,
    const float* __restrict__ Wo, const float* __restrict__ Rm,
    ushort_t* __restrict__ Xb, ushort_t* __restrict__ Wcat,
    ushort_t* __restrict__ Wo16, ushort_t* __restrict__ Rbf)
{
    int bid = blockIdx.x;
    const float* src; ushort_t* dst; int base;
    if (bid < 8192)       { src = hs; dst = Xb;              base = bid; }
    else if (bid < 12288) { src = Wq; dst = Wcat;            base = bid - 8192; }
    else if (bid < 14336) { src = Wk; dst = Wcat + 4194304;  base = bid - 12288; }
    else if (bid < 16384) { src = Wv; dst = Wcat + 6291456;  base = bid - 14336; }
    else if (bid < 20480) { src = Wo; dst = Wo16;            base = bid - 16384; }
    else                  { src = Rm; dst = Rbf;             base = bid - 20480; }
    int i = (base * 256 + threadIdx.x) * 4;
    float4 v = *reinterpret_cast<const float4*>(src + i);
    ushort4 o;
    o.x = f2bf(v.x); o.y = f2bf(v.y); o.z = f2bf(v.z); o.w = f2bf(v.w);
    *reinterpret_cast<ushort4*>(dst + i) = o;
}

// ---------- concatenated qkv bias ----------
__global__ void build_bcat_kernel(const float* __restrict__ bq,
                                  const float* __restrict__ bk,
                                  const float* __restrict__ bv,
                                  float* __restrict__ bcat)
{
    int i = blockIdx.x * 256 + threadIdx.x;
    float v = (i < 2048) ? bq[i] : (i < 3072) ? bk[i - 2048] : bv[i - 3072];
    bcat[i] = v;
}

// ================= 8-phase 256x256 GEMM (T1+T2+T3+T4+T5) ==================
// C[M,N] = A[M,K] @ B[N,K]^T + bias.  512 thr = 8 waves (2m x 4n), BK=64,
// 2-deep K-tile LDS dbuf (128 KiB), half-tile staging 1/phase, counted vmcnt
// at p3/p7 closes (BEFORE barrier -> cross-wave landing guarantee), chunk-XOR
// swizzle c^=(r&7) both-sides, setprio around each 16-MFMA cluster.
// LDS buffer b at b*65536: A half0 +0, A half1 +16384, B h0 +32768, B h1 +49152.
#define CLOSE_PLAIN __builtin_amdgcn_s_barrier()
#define CLOSE_VM(nn) do { asm volatile("s_waitcnt vmcnt(%0)" :: "n"(nn) : "memory"); \
                          __builtin_amdgcn_s_barrier(); } while (0)

template<int KC, bool STORE_BF16>
__global__ __launch_bounds__(512, 2) void gemm8p_kernel(
    const ushort_t* __restrict__ A, const ushort_t* __restrict__ B,
    const float* __restrict__ bias, void* __restrict__ C,
    const int M, const int N)
{
    constexpr int NT = KC / 64;          // K-tiles
    constexpr int NI = NT / 2;           // iterations (2 tiles each)
    static_assert(NT % 2 == 0 && NI >= 3, "need even NT >= 6");
    __shared__ alignas(16) char lds[131072];

    const int tid  = threadIdx.x;
    const int wid  = tid >> 6;
    const int lane = tid & 63;
    const int wm = wid >> 2, wn = wid & 3;

    // T1: XCD rect mapping (grid must be (M/256)*(N/256) == 256)
    const int RX = (M / 256) >> 2;
    const int x  = blockIdx.x & 7;
    const int kb = blockIdx.x >> 3;
    const int mb = (x % RX) * 4 + (kb >> 3);
    const int nb = (x / RX) * 8 + (kb & 7);
    const int am0 = mb * 256, bn0 = nb * 256;

    // staging constants: thread covers row sr3 (of 64-row issue block), chunk c8
    const int sr3 = tid >> 3;
    const int c8  = tid & 7;
    const int cs  = c8 ^ (sr3 & 7);          // swizzled SOURCE chunk
    const long K2 = (long)KC * 2;
    const char* agp = (const char*)A + (size_t)(am0 + sr3) * K2 + cs * 16;
    const char* bgp = (const char*)B + (size_t)(bn0 + sr3) * K2 + cs * 16;
    const int ldsw = wid << 10;              // wave-uniform LDS sub-base

    // frag-read constants (swizzled chunk on read side)
    const int fr = lane & 15, fc = lane >> 4;
    const int sw0 = ((fc)     ^ (fr & 7)) * 16;   // k-chunk 0
    const int sw1 = ((4 + fc) ^ (fr & 7)) * 16;   // k-chunk 1
    const int abase = wm * 16384 + fr * 128;      // + mg*2048 + sw
    const int bbase = 32768 + wn * 8192 + fr * 128;

    f32x4 acc[8][4] = {};
    bf16x8 bf[4];

    // stage one half-tile (2 x async16/thread). halfoff: A0=0,A1=16384,B0=32768,B1=49152
    auto stage_half = [&](const char* gp, int h, int bufb, int halfoff, long kof) {
        char* lp = lds + bufb + halfoff + ldsw;
        const char* g = gp + (size_t)(h * 128) * K2 + kof;
        async16(g, lp);
        async16(g + (size_t)64 * K2, lp + 8192);
    };
#define SA0(T) stage_half(agp, 0, ((T) & 1) * 65536, 0,     (long)(T) * 128)
#define SA1(T) stage_half(agp, 1, ((T) & 1) * 65536, 16384, (long)(T) * 128)
#define SB0(T) stage_half(bgp, 0, ((T) & 1) * 65536, 32768, (long)(T) * 128)
#define SB1(T) stage_half(bgp, 1, ((T) & 1) * 65536, 49152, (long)(T) * 128)

// one phase: ds_reads + stage + lgkm-drain + barrier + MFMA cluster + close
#define PH(h, kc, bufb, STG, CLOSE) do {                                      \
    const char* lp_ = lds + (bufb);                                           \
    const int sw_ = (kc) ? sw1 : sw0;                                         \
    if ((h) == 0) {                                                           \
        _Pragma("unroll") for (int n = 0; n < 4; ++n)                         \
            bf[n] = *(const bf16x8*)(lp_ + bbase + n * 2048 + sw_);           \
    }                                                                         \
    bf16x8 af_[4];                                                            \
    _Pragma("unroll") for (int j = 0; j < 4; ++j)                             \
        af_[j] = *(const bf16x8*)(lp_ + abase + ((h) * 4 + j) * 2048 + sw_);  \
    STG;                                                                      \
    asm volatile("s_waitcnt lgkmcnt(0)" ::: "memory");                        \
    __builtin_amdgcn_s_barrier();                                             \
    __builtin_amdgcn_s_setprio(1);                                            \
    _Pragma("unroll") for (int j = 0; j < 4; ++j)                             \
    _Pragma("unroll") for (int n = 0; n < 4; ++n)                             \
        acc[(h) * 4 + j][n] = __builtin_amdgcn_mfma_f32_16x16x32_bf16(        \
            af_[j], bf[n], acc[(h) * 4 + j][n], 0, 0, 0);                     \
    __builtin_amdgcn_s_setprio(0);                                            \
    CLOSE;                                                                    \
} while (0)

    // prologue: tiles 0 and 1 fully staged; t0 guaranteed landed for all waves
    SA0(0); SA1(0); SB0(0); SB1(0);
    SA0(1); SA1(1); SB0(1); SB1(1);
    wait_barrier<8>();                       // t0 landed (every wave <=8 out)

    // iter 0 (t=0): p0-p2 stage nothing (t1 staged in prologue)
    PH(0, 0, 0,      (void)0,  CLOSE_PLAIN);
    PH(1, 0, 0,      (void)0,  CLOSE_PLAIN);
    PH(0, 1, 0,      (void)0,  CLOSE_PLAIN);
    PH(1, 1, 0,      SB0(2),   CLOSE_VM(2));
    PH(0, 0, 65536,  SB1(2),   CLOSE_PLAIN);
    PH(1, 0, 65536,  SA0(2),   CLOSE_PLAIN);
    PH(0, 1, 65536,  SA1(2),   CLOSE_PLAIN);
    PH(1, 1, 65536,  SB0(3),   CLOSE_VM(2));

    // uniform iters 1..NI-2
    for (int i = 1; i <= NI - 2; ++i) {
        const int t = 2 * i;
        PH(0, 0, 0,      SB1(t + 1), CLOSE_PLAIN);
        PH(1, 0, 0,      SA0(t + 1), CLOSE_PLAIN);
        PH(0, 1, 0,      SA1(t + 1), CLOSE_PLAIN);
        PH(1, 1, 0,      SB0(t + 2), CLOSE_VM(2));
        PH(0, 0, 65536,  SB1(t + 2), CLOSE_PLAIN);
        PH(1, 0, 65536,  SA0(t + 2), CLOSE_PLAIN);
        PH(0, 1, 65536,  SA1(t + 2), CLOSE_PLAIN);
        PH(1, 1, 65536,  SB0(t + 3), CLOSE_VM(2));
    }

    // final iter (t = NT-2): finish staging tile NT-1 at p0-p2; vmcnt(0) at p3
    {
        constexpr int T1 = NT - 1;
        PH(0, 0, 0,      SB1(T1),  CLOSE_PLAIN);
        PH(1, 0, 0,      SA0(T1),  CLOSE_PLAIN);
        PH(0, 1, 0,      SA1(T1),  CLOSE_PLAIN);
        PH(1, 1, 0,      (void)0,  CLOSE_VM(0));
        PH(0, 0, 65536,  (void)0,  CLOSE_PLAIN);
        PH(1, 0, 65536,  (void)0,  CLOSE_PLAIN);
        PH(0, 1, 65536,  (void)0,  CLOSE_PLAIN);
        PH(1, 1, 65536,  (void)0,  CLOSE_PLAIN);
    }

    // epilogue: C/D layout col = lane&15, row = (lane>>4)*4 + reg
    const int crow0 = fc << 2;
#pragma unroll
    for (int m = 0; m < 8; ++m) {
        const int row_b = am0 + wm * 128 + m * 16 + crow0;
#pragma unroll
        for (int n = 0; n < 4; ++n) {
            const int col = bn0 + wn * 64 + n * 16 + fr;
            const float bs = bias[col];
#pragma unroll
            for (int r = 0; r < 4; ++r) {
                const float v = acc[m][n][r] + bs;
                if (STORE_BF16)
                    ((ushort_t*)C)[(size_t)(row_b + r) * N + col] = f2bf(v);
                else
                    ((float*)C)[(size_t)(row_b + r) * N + col] = v;
            }
        }
    }
#undef PH
#undef SA0
#undef SA1
#undef SB0
#undef SB1
}

// ---------- R4 pipelined GEMM (kept for GEMM2: BM=128) ----------
template<int BM, int KC, bool STORE_BF16>
__global__ __launch_bounds__(512, 2) void gemm_pipe_kernel(
    const ushort_t* __restrict__ A, const ushort_t* __restrict__ B,
    const float* __restrict__ bias, void* __restrict__ C,
    const int M, const int N)
{
    constexpr int MFRAG = BM / 32;
    constexpr int ISS_A = BM / 128;
    constexpr int ISS   = ISS_A + 2;
    constexpr int ABYT  = BM * 64;
    constexpr int AW    = BM * 32;
    constexpr int BUFB  = ABYT + 16384;
    constexpr int NT    = KC >> 5;
    static_assert(NT >= 6 && (NT & 1) == 0, "tail peel needs even NT>=6");
    __shared__ alignas(16) char lds[4 * BUFB];

    const int tid  = threadIdx.x;
    const int wid  = tid >> 6;
    const int lane = tid & 63;
    const int wm = wid >> 2, wn = wid & 3;

    const int NBM = M / BM;
    const int RX  = NBM >> 2;
    const int x  = blockIdx.x & 7;
    const int kk = blockIdx.x >> 3;
    const int mb = (x % RX) * 4 + (kk >> 3);
    const int nb = (x / RX) * 8 + (kk & 7);
    const int am0 = mb * BM, bn0 = nb * 256;

    const int sr  = tid >> 2;
    const int scb = (tid & 3) ^ ((sr >> 1) & 3);
    const size_t argb = (size_t)(am0 + sr) * KC + scb * 8;
    const size_t brgb = (size_t)(bn0 + sr) * KC + scb * 8;
    const int ldswave = wid << 10;

    const int fr = lane & 15;
    const int fc = lane >> 4;
    const int rswz  = (fc ^ ((fr >> 1) & 3)) << 4;
    const int aoff0 = wm * AW + fr * 64 + rswz;
    const int boff0 = ABYT + wn * 4096 + fr * 64 + rswz;

    f32x4 acc[MFRAG][4] = {};
    bf16x8 afA[MFRAG], bfA[4], afB[MFRAG], bfB[4];

    auto stage = [&](int t) {
        char* lp = lds + (t & 3) * BUFB;
        const size_t kof = (size_t)t << 5;
#pragma unroll
        for (int i = 0; i < ISS_A; ++i)
            async16(A + argb + (size_t)(i * 128) * KC + kof,
                    lp + i * 8192 + ldswave);
#pragma unroll
        for (int i = 0; i < 2; ++i)
            async16(B + brgb + (size_t)(i * 128) * KC + kof,
                    lp + ABYT + i * 8192 + ldswave);
    };

    auto ldfrags = [&](int t, bf16x8 (&af)[MFRAG], bf16x8 (&bf)[4]) {
        const char* lp = lds + (t & 3) * BUFB;
#pragma unroll
        for (int n = 0; n < 4; ++n)
            bf[n] = *(const bf16x8*)(lp + boff0 + n * 1024);
#pragma unroll
        for (int m = 0; m < MFRAG; ++m)
            af[m] = *(const bf16x8*)(lp + aoff0 + m * 1024);
    };

    auto domfma = [&](bf16x8 (&af)[MFRAG], bf16x8 (&bf)[4]) {
        __builtin_amdgcn_s_setprio(1);
#pragma unroll
        for (int m = 0; m < MFRAG; ++m)
#pragma unroll
            for (int n = 0; n < 4; ++n)
                acc[m][n] = __builtin_amdgcn_mfma_f32_16x16x32_bf16(
                    af[m], bf[n], acc[m][n], 0, 0, 0);
        __builtin_amdgcn_s_setprio(0);
        asm volatile("s_waitcnt lgkmcnt(0)" ::: "memory");
    };

    stage(0); stage(1); stage(2);
    wait_barrier<2 * ISS>();
    ldfrags(0, afA, bfA);

    for (int t = 0; t < NT - 4; t += 2) {
        stage(t + 3);
        wait_barrier<2 * ISS>();
        ldfrags(t + 1, afB, bfB);
        domfma(afA, bfA);
        stage(t + 4);
        wait_barrier<2 * ISS>();
        ldfrags(t + 2, afA, bfA);
        domfma(afB, bfB);
    }
    stage(NT - 1);
    wait_barrier<2 * ISS>();
    ldfrags(NT - 3, afB, bfB);
    domfma(afA, bfA);
    wait_barrier<ISS>();
    ldfrags(NT - 2, afA, bfA);
    domfma(afB, bfB);
    wait_barrier<0>();
    ldfrags(NT - 1, afB, bfB);
    domfma(afA, bfA);
    domfma(afB, bfB);

    const int crow0 = fc << 2;
#pragma unroll
    for (int m = 0; m < MFRAG; ++m) {
        const int row_b = am0 + wm * (BM / 2) + m * 16 + crow0;
#pragma unroll
        for (int n = 0; n < 4; ++n) {
            const int col = bn0 + wn * 64 + n * 16 + fr;
            const float bs = bias[col];
#pragma unroll
            for (int r = 0; r < 4; ++r) {
                const float v = acc[m][n][r] + bs;
                if (STORE_BF16)
                    ((ushort_t*)C)[(size_t)(row_b + r) * N + col] = f2bf(v);
                else
                    ((float*)C)[(size_t)(row_b + r) * N + col] = v;
            }
        }
    }
}

// ---------- stage A1: RoPE + unit-normalize -> xnorm bf16 ----------
__global__ __launch_bounds__(256) void rope_norm_kernel(
    const ushort_t* __restrict__ qkv, ushort_t* __restrict__ xnorm)
{
    const int tok = blockIdx.x;
    const int s = tok & 2047;
    const int wid = threadIdx.x >> 6, lane = threadIdx.x & 63;

    float invf = exp2f(-(float)lane * (13.287712379549449f / 64.0f));
    float ang = (float)s * invf;
    float sn, cs;
    sincosf(ang, &sn, &cs);

    const ushort_t* row = qkv + (size_t)tok * 4096;
#pragma unroll
    for (int i = 0; i < 6; ++i) {
        int vec = wid * 6 + i;
        int base = (vec < 16) ? vec * 128 : 2048 + (vec - 16) * 128;
        float a = bf2f(row[base + lane]);
        float c = bf2f(row[base + lane + 64]);
        float ra = a * cs - c * sn;
        float rc = c * cs + a * sn;
        float ss2 = ra * ra + rc * rc;
#pragma unroll
        for (int off = 32; off; off >>= 1) ss2 += __shfl_xor(ss2, off);
        float inv = 1.0f / fmaxf(sqrtf(ss2), 1e-6f);
        ushort_t* orow = xnorm + (size_t)tok * 3072 + vec * 128;
        orow[lane]      = f2bf(ra * inv);
        orow[lane + 64] = f2bf(rc * inv);
    }
}

// ---------- stage A2: feats = [sin,cos](xnorm @ R^T)/sqrt(F), in-place ----------
__global__ __launch_bounds__(256) void feats_kernel(
    ushort_t* __restrict__ xnorm, const ushort_t* __restrict__ Rbf)
{
    const int wid = threadIdx.x >> 6, lane = threadIdx.x & 63;
    const int r0 = blockIdx.x * 128 + wid * 32;
    const int fr = lane & 15, fk = (lane >> 4) << 3;

    bf16x8 bfv[4][4];
#pragma unroll
    for (int n = 0; n < 4; ++n)
#pragma unroll
        for (int kk = 0; kk < 4; ++kk)
            bfv[n][kk] = *reinterpret_cast<const bf16x8*>(
                Rbf + (n * 16 + fr) * 128 + kk * 32 + fk);

    f32x4 acc[2][4] = {};
#pragma unroll
    for (int m = 0; m < 2; ++m) {
#pragma unroll
        for (int kk = 0; kk < 4; ++kk) {
            bf16x8 af = *reinterpret_cast<const bf16x8*>(
                xnorm + (size_t)(r0 + m * 16 + fr) * 128 + kk * 32 + fk);
#pragma unroll
            for (int n = 0; n < 4; ++n)
                acc[m][n] = __builtin_amdgcn_mfma_f32_16x16x32_bf16(
                    af, bfv[n][kk], acc[m][n], 0, 0, 0);
        }
    }

    const int crow0 = (lane >> 4) << 2;
#pragma unroll
    for (int m = 0; m < 2; ++m)
#pragma unroll
        for (int n = 0; n < 4; ++n) {
            int e = n * 16 + fr;
#pragma unroll
            for (int r = 0; r < 4; ++r) {
                int row = r0 + m * 16 + crow0 + r;
                float p = acc[m][n][r];
                float sp, cp;
                sincosf(p, &sp, &cp);
                ushort_t* orow = xnorm + (size_t)row * 128;
                orow[e]      = f2bf(sp * 0.08838834764831845f);
                orow[e + 64] = f2bf(cp * 0.08838834764831845f);
            }
        }
}

// ---------- stage A3: per-token head contraction ----------
__global__ __launch_bounds__(256) void ctx_kernel(
    const ushort_t* __restrict__ feats, const ushort_t* __restrict__ qkv,
    ushort_t* __restrict__ ctx)
{
    __shared__ float qp[16][132];
    __shared__ float kp[8][132];
    __shared__ float vsm[8][132];
    __shared__ float Apart[2][16][8];
    __shared__ float Am[16][8];

    const int tok = blockIdx.x;
    const int b = tok >> 11, s = tok & 2047;
    const int tid = threadIdx.x;
    const ushort_t* frow = feats + (size_t)tok * 3072;
    const ushort_t* vrow = qkv + (size_t)tok * 4096 + 3072;

    for (int idx = tid; idx < 3072; idx += 256) {
        int vec = idx >> 7, d = idx & 127;
        float f = bf2f(frow[idx]);
        if (vec < 16) qp[vec][d] = f; else kp[vec - 16][d] = f;
    }
    for (int idx = tid; idx < 1024; idx += 256)
        vsm[idx >> 7][idx & 127] = bf2f(vrow[idx]);
    __syncthreads();

    {
        int half = tid >> 7, pid = tid & 127;
        int h = pid >> 3, hk = pid & 7;
        int f0 = half * 64;
        float acc = 0.f;
#pragma unroll
        for (int f = 0; f < 64; f += 4) {
            float4 qa = *reinterpret_cast<const float4*>(&qp[h][f0 + f]);
            float4 ka = *reinterpret_cast<const float4*>(&kp[hk][f0 + f]);
            acc = fmaf(qa.x, ka.x, acc); acc = fmaf(qa.y, ka.y, acc);
            acc = fmaf(qa.z, ka.z, acc); acc = fmaf(qa.w, ka.w, acc);
        }
        Apart[half][h][hk] = acc;
    }
    __syncthreads();
    if (tid < 128) {
        int h = tid >> 3, hk = tid & 7;
        Am[h][hk] = 2.0f * (Apart[0][h][hk] + Apart[1][h][hk]);
    }
    __syncthreads();

    for (int idx = tid; idx < 2048; idx += 256) {
        int h = idx >> 7, d = idx & 127;
        float acc = 0.f;
#pragma unroll
        for (int hk = 0; hk < 8; ++hk) acc = fmaf(Am[h][hk], vsm[hk][d], acc);
        int row = (b << 11) + (h << 7) + (s >> 4);
        int col = ((s & 15) << 7) + d;
        ctx[(size_t)row * 2048 + col] = f2bf(acc);
    }
}

// ---------- launch ----------
extern "C" void kernel_launch(void* const* d_in, const int* in_sizes, int n_in,
                              void* d_out, int out_size, void* d_ws, size_t ws_size,
                              hipStream_t stream)
{
    const float* hs = (const float*)d_in[0];
    const float* Wq = (const float*)d_in[1];
    const float* bq = (const float*)d_in[2];
    const float* Wk = (const float*)d_in[3];
    const float* bk = (const float*)d_in[4];
    const float* Wv = (const float*)d_in[5];
    const float* bv = (const float*)d_in[6];
    const float* Wo = (const float*)d_in[7];
    const float* bo = (const float*)d_in[8];
    const float* Rm = (const float*)d_in[9];
    float* out = (float*)d_out;

    char* ws = (char*)d_ws;
    ushort_t* Xb   = (ushort_t*)(ws);                 // 4096x2048 bf16
    ushort_t* Wcat = (ushort_t*)(ws + 16777216);      // 4096x2048 bf16 (Wq;Wk;Wv)
    ushort_t* Wo16 = (ushort_t*)(ws + 33554432);      // 2048x2048 bf16
    ushort_t* qkv  = (ushort_t*)(ws + 41943040);      // 4096x4096 bf16
    ushort_t* ctx  = (ushort_t*)(ws + 75497472);      // 4096x2048 bf16 (scrambled)
    float*    bcat = (float*)   (ws + 92274688);      // 4096 f32
    ushort_t* Rbf  = (ushort_t*)(ws + 92291072);      // 64x128 bf16
    ushort_t* xnorm = (ushort_t*)(ws);                // reuses Xb+Wcat region

    cast_all_kernel<<<20488, 256, 0, stream>>>(hs, Wq, Wk, Wv, Wo, Rm,
                                               Xb, Wcat, Wo16, Rbf);
    build_bcat_kernel<<<16, 256, 0, stream>>>(bq, bk, bv, bcat);

    // qkv = X @ [Wq;Wk;Wv]^T + bcat   (M=4096, N=4096, K=2048) — 8-phase
    gemm8p_kernel<2048, true><<<256, 512, 0, stream>>>(
        Xb, Wcat, bcat, qkv, 4096, 4096);

    rope_norm_kernel<<<4096, 256, 0, stream>>>(qkv, xnorm);
    feats_kernel<<<768, 256, 0, stream>>>(xnorm, Rbf);
    ctx_kernel<<<4096, 256, 0, stream>>>(xnorm, qkv, ctx);

    // out = ctx @ Wo^T + bo   (M=4096, N=2048, K=2048), fp32 out
    gemm_pipe_kernel<128, 2048, false><<<256, 512, 0, stream>>>(
        ctx, Wo16, bo, out, 4096, 2048);
}

// Round 6
// 169.129 us; speedup vs baseline: 2.1214x; 1.0306x over previous
//
#include <hip/hip_runtime.h>
#include <stdint.h>

typedef unsigned short ushort_t;
typedef __bf16 bf16x8 __attribute__((ext_vector_type(8)));
typedef float f32x4 __attribute__((ext_vector_type(4)));
typedef unsigned int u32;

// ---------- bf16 helpers (manual, RNE) ----------
__device__ __forceinline__ float bf2f(ushort_t u) {
    union { u32 u; float f; } x; x.u = ((u32)u) << 16; return x.f;
}
__device__ __forceinline__ ushort_t f2bf(float f) {
    union { float f; u32 u; } x; x.f = f;
    u32 r = x.u + 0x7FFFu + ((x.u >> 16) & 1u);
    return (ushort_t)(r >> 16);
}

// ---------- async global->LDS, 16B per lane ----------
__device__ __forceinline__ void async16(const void* gp, void* lp) {
    __builtin_amdgcn_global_load_lds(
        (const __attribute__((address_space(1))) u32*)(gp),
        (__attribute__((address_space(3))) u32*)(lp),
        16, 0, 0);
}

template<int N>
__device__ __forceinline__ void wait_barrier() {
    asm volatile("s_waitcnt vmcnt(%0)\n\ts_barrier" :: "n"(N) : "memory");
}

// ---------- fused fp32 -> bf16 casts ----------
__global__ __launch_bounds__(256) void cast_all_kernel(
    const float* __restrict__ hs, const float* __restrict__ Wq,
    const float* __restrict__ Wk, const float* __restrict__ Wv,
    const float* __restrict__ Wo, const float* __restrict__ Rm,
    ushort_t* __restrict__ Xb, ushort_t* __restrict__ Wcat,
    ushort_t* __restrict__ Wo16, ushort_t* __restrict__ Rbf)
{
    int bid = blockIdx.x;
    const float* src; ushort_t* dst; int base;
    if (bid < 8192)       { src = hs; dst = Xb;              base = bid; }
    else if (bid < 12288) { src = Wq; dst = Wcat;            base = bid - 8192; }
    else if (bid < 14336) { src = Wk; dst = Wcat + 4194304;  base = bid - 12288; }
    else if (bid < 16384) { src = Wv; dst = Wcat + 6291456;  base = bid - 14336; }
    else if (bid < 20480) { src = Wo; dst = Wo16;            base = bid - 16384; }
    else                  { src = Rm; dst = Rbf;             base = bid - 20480; }
    int i = (base * 256 + threadIdx.x) * 4;
    float4 v = *reinterpret_cast<const float4*>(src + i);
    ushort4 o;
    o.x = f2bf(v.x); o.y = f2bf(v.y); o.z = f2bf(v.z); o.w = f2bf(v.w);
    *reinterpret_cast<ushort4*>(dst + i) = o;
}

// ---------- concatenated qkv bias ----------
__global__ void build_bcat_kernel(const float* __restrict__ bq,
                                  const float* __restrict__ bk,
                                  const float* __restrict__ bv,
                                  float* __restrict__ bcat)
{
    int i = blockIdx.x * 256 + threadIdx.x;
    float v = (i < 2048) ? bq[i] : (i < 3072) ? bk[i - 2048] : bv[i - 3072];
    bcat[i] = v;
}

// ================= 8-phase BMx256 GEMM (T1+T2+T3+T4+T5) ==================
// C[M,N] = A[M,K] @ B[N,K]^T + bias.  512 thr = 8 waves (2m x 4n), BK=64,
// 2-deep K-tile LDS dbuf, half-tile staging 1/phase, counted vmcnt at p3/p7,
// chunk-XOR swizzle c^=(r&7) both-sides, setprio around each MFMA cluster.
// Phase order = m201 template: issue ds_reads -> stage -> s_barrier ->
// lgkmcnt(0) (drain overlaps barrier wait) -> MFMA -> close.
// Grid must be MBLK*NBLK == 256 blocks.
#define CLOSE_PLAIN __builtin_amdgcn_s_barrier()
#define CLOSE_VM(nn) do { asm volatile("s_waitcnt vmcnt(%0)" :: "n"(nn) : "memory"); \
                          __builtin_amdgcn_s_barrier(); } while (0)

template<int BM, int MBLK, int NBLK, int KC, bool STORE_BF16>
__global__ __launch_bounds__(512, 2) void gemm8p_kernel(
    const ushort_t* __restrict__ A, const ushort_t* __restrict__ B,
    const float* __restrict__ bias, void* __restrict__ C,
    const int M, const int N)
{
    constexpr int NT  = KC / 64;         // K-tiles
    constexpr int NI  = NT / 2;          // iterations (2 tiles each)
    constexpr int MF2 = BM / 64;         // A-frags per phase
    constexpr int NFR = BM / 32;         // A-frags per wave total
    constexpr int AH  = BM * 64;         // A half-tile bytes ((BM/2) rows x 128B)
    constexpr int SH  = BM / 128;        // async16/thread per A half stage
    constexpr int BUF = 2 * AH + 32768;  // buffer stride
    constexpr int TI  = 2 * SH + 4;      // async16/thread per full tile
    static_assert(NT % 2 == 0 && NI >= 3, "need even NT >= 6");
    __shared__ alignas(16) char lds[2 * BUF];

    const int tid  = threadIdx.x;
    const int wid  = tid >> 6;
    const int lane = tid & 63;
    const int wm = wid >> 2, wn = wid & 3;

    // T1: bijective XCD rect mapping (8 XCDs; rect = RH m-blocks x 8 n-blocks)
    constexpr int XN  = NBLK / 8;        // XCD cols (>=1)
    constexpr int NXR = 8 / XN;          // XCD rows
    constexpr int RH  = MBLK / NXR;      // rect height
    const int x  = blockIdx.x & 7;
    const int kb = blockIdx.x >> 3;
    const int mb = (x % NXR) * RH + (kb >> 3);
    const int nb = (x / NXR) * 8 + (kb & 7);
    const int am0 = mb * BM, bn0 = nb * 256;

    // staging: thread covers row sr3 (of 64-row issue block), swizzled chunk
    const int sr3 = tid >> 3;
    const int c8  = tid & 7;
    const int cs  = c8 ^ (sr3 & 7);
    const long K2 = (long)KC * 2;
    const char* agp = (const char*)A + (size_t)(am0 + sr3) * K2 + cs * 16;
    const char* bgp = (const char*)B + (size_t)(bn0 + sr3) * K2 + cs * 16;
    const int ldsw = wid << 10;

    // frag-read constants (swizzled chunk on read side)
    const int fr = lane & 15, fc = lane >> 4;
    const int sw0 = ((fc)     ^ (fr & 7)) * 16;
    const int sw1 = ((4 + fc) ^ (fr & 7)) * 16;
    const int abase = wm * AH + fr * 128;
    const int bbase = 2 * AH + wn * 8192 + fr * 128;

    f32x4 acc[NFR][4] = {};
    bf16x8 bf[4];

    auto stage_half = [&](const char* gp, int rowoff, int bufb, int off,
                          long kof, int niss) {
        char* lp = lds + bufb + off + ldsw;
        const char* g = gp + (size_t)rowoff * K2 + kof;
#pragma unroll
        for (int i = 0; i < niss; ++i)
            async16(g + (size_t)(i * 64) * K2, lp + i * 8192);
    };
#define SA0(T) stage_half(agp, 0,      ((T) & 1) * BUF, 0,          (long)(T) * 128, SH)
#define SA1(T) stage_half(agp, BM / 2, ((T) & 1) * BUF, AH,         (long)(T) * 128, SH)
#define SB0(T) stage_half(bgp, 0,      ((T) & 1) * BUF, 2 * AH,     (long)(T) * 128, 2)
#define SB1(T) stage_half(bgp, 128,    ((T) & 1) * BUF, 2 * AH + 16384, (long)(T) * 128, 2)

// one phase: ds_reads + stage + barrier + lgkm-drain + MFMA cluster + close
#define PH(h, kc, bufb, STG, CLOSE) do {                                      \
    const char* lp_ = lds + (bufb);                                           \
    const int sw_ = (kc) ? sw1 : sw0;                                         \
    if ((h) == 0) {                                                           \
        _Pragma("unroll") for (int n = 0; n < 4; ++n)                         \
            bf[n] = *(const bf16x8*)(lp_ + bbase + n * 2048 + sw_);           \
    }                                                                         \
    bf16x8 af_[MF2];                                                          \
    _Pragma("unroll") for (int j = 0; j < MF2; ++j)                           \
        af_[j] = *(const bf16x8*)(lp_ + abase + ((h) * MF2 + j) * 2048 + sw_);\
    STG;                                                                      \
    __builtin_amdgcn_s_barrier();                                             \
    asm volatile("s_waitcnt lgkmcnt(0)" ::: "memory");                        \
    __builtin_amdgcn_s_setprio(1);                                            \
    _Pragma("unroll") for (int j = 0; j < MF2; ++j)                           \
    _Pragma("unroll") for (int n = 0; n < 4; ++n)                             \
        acc[(h) * MF2 + j][n] = __builtin_amdgcn_mfma_f32_16x16x32_bf16(      \
            af_[j], bf[n], acc[(h) * MF2 + j][n], 0, 0, 0);                   \
    __builtin_amdgcn_s_setprio(0);                                            \
    CLOSE;                                                                    \
} while (0)

    // prologue: tiles 0 and 1 fully staged; wait until tile 0 landed
    SA0(0); SA1(0); SB0(0); SB1(0);
    SA0(1); SA1(1); SB0(1); SB1(1);
    wait_barrier<TI>();

    // iter 0 (t=0): p0-p2 stage nothing (tile 1 staged in prologue)
    PH(0, 0, 0,    (void)0,  CLOSE_PLAIN);
    PH(1, 0, 0,    (void)0,  CLOSE_PLAIN);
    PH(0, 1, 0,    (void)0,  CLOSE_PLAIN);
    PH(1, 1, 0,    SB0(2),   CLOSE_VM(2));
    PH(0, 0, BUF,  SB1(2),   CLOSE_PLAIN);
    PH(1, 0, BUF,  SA0(2),   CLOSE_PLAIN);
    PH(0, 1, BUF,  SA1(2),   CLOSE_PLAIN);
    PH(1, 1, BUF,  SB0(3),   CLOSE_VM(2));

    // uniform iters 1..NI-2
    for (int i = 1; i <= NI - 2; ++i) {
        const int t = 2 * i;
        PH(0, 0, 0,    SB1(t + 1), CLOSE_PLAIN);
        PH(1, 0, 0,    SA0(t + 1), CLOSE_PLAIN);
        PH(0, 1, 0,    SA1(t + 1), CLOSE_PLAIN);
        PH(1, 1, 0,    SB0(t + 2), CLOSE_VM(2));
        PH(0, 0, BUF,  SB1(t + 2), CLOSE_PLAIN);
        PH(1, 0, BUF,  SA0(t + 2), CLOSE_PLAIN);
        PH(0, 1, BUF,  SA1(t + 2), CLOSE_PLAIN);
        PH(1, 1, BUF,  SB0(t + 3), CLOSE_VM(2));
    }

    // final iter (t = NT-2): finish staging tile NT-1 at p0-p2; vmcnt(0) at p3
    {
        constexpr int T1 = NT - 1;
        PH(0, 0, 0,    SB1(T1),  CLOSE_PLAIN);
        PH(1, 0, 0,    SA0(T1),  CLOSE_PLAIN);
        PH(0, 1, 0,    SA1(T1),  CLOSE_PLAIN);
        PH(1, 1, 0,    (void)0,  CLOSE_VM(0));
        PH(0, 0, BUF,  (void)0,  CLOSE_PLAIN);
        PH(1, 0, BUF,  (void)0,  CLOSE_PLAIN);
        PH(0, 1, BUF,  (void)0,  CLOSE_PLAIN);
        PH(1, 1, BUF,  (void)0,  CLOSE_PLAIN);
    }

    // epilogue: C/D layout col = lane&15, row = (lane>>4)*4 + reg
    const int crow0 = fc << 2;
#pragma unroll
    for (int m = 0; m < NFR; ++m) {
        const int row_b = am0 + wm * (BM / 2) + m * 16 + crow0;
#pragma unroll
        for (int n = 0; n < 4; ++n) {
            const int col = bn0 + wn * 64 + n * 16 + fr;
            const float bs = bias[col];
#pragma unroll
            for (int r = 0; r < 4; ++r) {
                const float v = acc[m][n][r] + bs;
                if (STORE_BF16)
                    ((ushort_t*)C)[(size_t)(row_b + r) * N + col] = f2bf(v);
                else
                    ((float*)C)[(size_t)(row_b + r) * N + col] = v;
            }
        }
    }
#undef PH
#undef SA0
#undef SA1
#undef SB0
#undef SB1
}

// ---------- stage A1: RoPE + unit-normalize -> xnorm bf16 ----------
__global__ __launch_bounds__(256) void rope_norm_kernel(
    const ushort_t* __restrict__ qkv, ushort_t* __restrict__ xnorm)
{
    const int tok = blockIdx.x;
    const int s = tok & 2047;
    const int wid = threadIdx.x >> 6, lane = threadIdx.x & 63;

    float invf = exp2f(-(float)lane * (13.287712379549449f / 64.0f));
    float ang = (float)s * invf;
    float sn, cs;
    sincosf(ang, &sn, &cs);

    const ushort_t* row = qkv + (size_t)tok * 4096;
#pragma unroll
    for (int i = 0; i < 6; ++i) {
        int vec = wid * 6 + i;
        int base = (vec < 16) ? vec * 128 : 2048 + (vec - 16) * 128;
        float a = bf2f(row[base + lane]);
        float c = bf2f(row[base + lane + 64]);
        float ra = a * cs - c * sn;
        float rc = c * cs + a * sn;
        float ss2 = ra * ra + rc * rc;
#pragma unroll
        for (int off = 32; off; off >>= 1) ss2 += __shfl_xor(ss2, off);
        float inv = 1.0f / fmaxf(sqrtf(ss2), 1e-6f);
        ushort_t* orow = xnorm + (size_t)tok * 3072 + vec * 128;
        orow[lane]      = f2bf(ra * inv);
        orow[lane + 64] = f2bf(rc * inv);
    }
}

// ---------- stage A2: feats = [sin,cos](xnorm @ R^T)/sqrt(F), in-place ----------
__global__ __launch_bounds__(256) void feats_kernel(
    ushort_t* __restrict__ xnorm, const ushort_t* __restrict__ Rbf)
{
    const int wid = threadIdx.x >> 6, lane = threadIdx.x & 63;
    const int r0 = blockIdx.x * 128 + wid * 32;
    const int fr = lane & 15, fk = (lane >> 4) << 3;

    bf16x8 bfv[4][4];
#pragma unroll
    for (int n = 0; n < 4; ++n)
#pragma unroll
        for (int kk = 0; kk < 4; ++kk)
            bfv[n][kk] = *reinterpret_cast<const bf16x8*>(
                Rbf + (n * 16 + fr) * 128 + kk * 32 + fk);

    f32x4 acc[2][4] = {};
#pragma unroll
    for (int m = 0; m < 2; ++m) {
#pragma unroll
        for (int kk = 0; kk < 4; ++kk) {
            bf16x8 af = *reinterpret_cast<const bf16x8*>(
                xnorm + (size_t)(r0 + m * 16 + fr) * 128 + kk * 32 + fk);
#pragma unroll
            for (int n = 0; n < 4; ++n)
                acc[m][n] = __builtin_amdgcn_mfma_f32_16x16x32_bf16(
                    af, bfv[n][kk], acc[m][n], 0, 0, 0);
        }
    }

    const int crow0 = (lane >> 4) << 2;
#pragma unroll
    for (int m = 0; m < 2; ++m)
#pragma unroll
        for (int n = 0; n < 4; ++n) {
            int e = n * 16 + fr;
#pragma unroll
            for (int r = 0; r < 4; ++r) {
                int row = r0 + m * 16 + crow0 + r;
                float p = acc[m][n][r];
                float sp, cp;
                sincosf(p, &sp, &cp);
                ushort_t* orow = xnorm + (size_t)row * 128;
                orow[e]      = f2bf(sp * 0.08838834764831845f);
                orow[e + 64] = f2bf(cp * 0.08838834764831845f);
            }
        }
}

// ---------- stage A3: per-token head contraction ----------
__global__ __launch_bounds__(256) void ctx_kernel(
    const ushort_t* __restrict__ feats, const ushort_t* __restrict__ qkv,
    ushort_t* __restrict__ ctx)
{
    __shared__ float qp[16][132];
    __shared__ float kp[8][132];
    __shared__ float vsm[8][132];
    __shared__ float Apart[2][16][8];
    __shared__ float Am[16][8];

    const int tok = blockIdx.x;
    const int b = tok >> 11, s = tok & 2047;
    const int tid = threadIdx.x;
    const ushort_t* frow = feats + (size_t)tok * 3072;
    const ushort_t* vrow = qkv + (size_t)tok * 4096 + 3072;

    for (int idx = tid; idx < 3072; idx += 256) {
        int vec = idx >> 7, d = idx & 127;
        float f = bf2f(frow[idx]);
        if (vec < 16) qp[vec][d] = f; else kp[vec - 16][d] = f;
    }
    for (int idx = tid; idx < 1024; idx += 256)
        vsm[idx >> 7][idx & 127] = bf2f(vrow[idx]);
    __syncthreads();

    {
        int half = tid >> 7, pid = tid & 127;
        int h = pid >> 3, hk = pid & 7;
        int f0 = half * 64;
        float acc = 0.f;
#pragma unroll
        for (int f = 0; f < 64; f += 4) {
            float4 qa = *reinterpret_cast<const float4*>(&qp[h][f0 + f]);
            float4 ka = *reinterpret_cast<const float4*>(&kp[hk][f0 + f]);
            acc = fmaf(qa.x, ka.x, acc); acc = fmaf(qa.y, ka.y, acc);
            acc = fmaf(qa.z, ka.z, acc); acc = fmaf(qa.w, ka.w, acc);
        }
        Apart[half][h][hk] = acc;
    }
    __syncthreads();
    if (tid < 128) {
        int h = tid >> 3, hk = tid & 7;
        Am[h][hk] = 2.0f * (Apart[0][h][hk] + Apart[1][h][hk]);
    }
    __syncthreads();

    for (int idx = tid; idx < 2048; idx += 256) {
        int h = idx >> 7, d = idx & 127;
        float acc = 0.f;
#pragma unroll
        for (int hk = 0; hk < 8; ++hk) acc = fmaf(Am[h][hk], vsm[hk][d], acc);
        int row = (b << 11) + (h << 7) + (s >> 4);
        int col = ((s & 15) << 7) + d;
        ctx[(size_t)row * 2048 + col] = f2bf(acc);
    }
}

// ---------- launch ----------
extern "C" void kernel_launch(void* const* d_in, const int* in_sizes, int n_in,
                              void* d_out, int out_size, void* d_ws, size_t ws_size,
                              hipStream_t stream)
{
    const float* hs = (const float*)d_in[0];
    const float* Wq = (const float*)d_in[1];
    const float* bq = (const float*)d_in[2];
    const float* Wk = (const float*)d_in[3];
    const float* bk = (const float*)d_in[4];
    const float* Wv = (const float*)d_in[5];
    const float* bv = (const float*)d_in[6];
    const float* Wo = (const float*)d_in[7];
    const float* bo = (const float*)d_in[8];
    const float* Rm = (const float*)d_in[9];
    float* out = (float*)d_out;

    char* ws = (char*)d_ws;
    ushort_t* Xb   = (ushort_t*)(ws);                 // 4096x2048 bf16
    ushort_t* Wcat = (ushort_t*)(ws + 16777216);      // 4096x2048 bf16 (Wq;Wk;Wv)
    ushort_t* Wo16 = (ushort_t*)(ws + 33554432);      // 2048x2048 bf16
    ushort_t* qkv  = (ushort_t*)(ws + 41943040);      // 4096x4096 bf16
    ushort_t* ctx  = (ushort_t*)(ws + 75497472);      // 4096x2048 bf16 (scrambled)
    float*    bcat = (float*)   (ws + 92274688);      // 4096 f32
    ushort_t* Rbf  = (ushort_t*)(ws + 92291072);      // 64x128 bf16
    ushort_t* xnorm = (ushort_t*)(ws);                // reuses Xb+Wcat region

    cast_all_kernel<<<20488, 256, 0, stream>>>(hs, Wq, Wk, Wv, Wo, Rm,
                                               Xb, Wcat, Wo16, Rbf);
    build_bcat_kernel<<<16, 256, 0, stream>>>(bq, bk, bv, bcat);

    // qkv = X @ [Wq;Wk;Wv]^T + bcat   (M=4096, N=4096, K=2048) — 8-phase 256x256
    gemm8p_kernel<256, 16, 16, 2048, true><<<256, 512, 0, stream>>>(
        Xb, Wcat, bcat, qkv, 4096, 4096);

    rope_norm_kernel<<<4096, 256, 0, stream>>>(qkv, xnorm);
    feats_kernel<<<768, 256, 0, stream>>>(xnorm, Rbf);
    ctx_kernel<<<4096, 256, 0, stream>>>(xnorm, qkv, ctx);

    // out = ctx @ Wo^T + bo   (M=4096, N=2048, K=2048) — 8-phase 128x256
    gemm8p_kernel<128, 32, 8, 2048, false><<<256, 512, 0, stream>>>(
        ctx, Wo16, bo, out, 4096, 2048);
}

// Round 7
// 144.753 us; speedup vs baseline: 2.4786x; 1.1684x over previous
//
#include <hip/hip_runtime.h>
#include <stdint.h>

typedef unsigned short ushort_t;
typedef __bf16 bf16x8 __attribute__((ext_vector_type(8)));
typedef float f32x4 __attribute__((ext_vector_type(4)));
typedef unsigned int u32;

// ---------- bf16 helpers (manual, RNE) ----------
__device__ __forceinline__ float bf2f(ushort_t u) {
    union { u32 u; float f; } x; x.u = ((u32)u) << 16; return x.f;
}
__device__ __forceinline__ ushort_t f2bf(float f) {
    union { float f; u32 u; } x; x.f = f;
    u32 r = x.u + 0x7FFFu + ((x.u >> 16) & 1u);
    return (ushort_t)(r >> 16);
}

// ---------- async global->LDS, 16B per lane ----------
__device__ __forceinline__ void async16(const void* gp, void* lp) {
    __builtin_amdgcn_global_load_lds(
        (const __attribute__((address_space(1))) u32*)(gp),
        (__attribute__((address_space(3))) u32*)(lp),
        16, 0, 0);
}

template<int N>
__device__ __forceinline__ void wait_barrier() {
    asm volatile("s_waitcnt vmcnt(%0)\n\ts_barrier" :: "n"(N) : "memory");
}

// ---------- fused fp32 -> bf16 casts + bias concat (one launch) ----------
// 2048 floats per block (256 thr x 8). Ranges:
// hs[0,4096) Wq[4096,6144) Wk[6144,7168) Wv[7168,8192) Wo[8192,10240)
// R[10240,10244) bcat-build block == 10244.
__global__ __launch_bounds__(256) void cast_all_kernel(
    const float* __restrict__ hs, const float* __restrict__ Wq,
    const float* __restrict__ Wk, const float* __restrict__ Wv,
    const float* __restrict__ Wo, const float* __restrict__ Rm,
    const float* __restrict__ bq, const float* __restrict__ bk,
    const float* __restrict__ bv,
    ushort_t* __restrict__ Xb, ushort_t* __restrict__ Wcat,
    ushort_t* __restrict__ Wo16, ushort_t* __restrict__ Rbf,
    float* __restrict__ bcat)
{
    int bid = blockIdx.x;
    if (bid == 10244) {   // concatenated qkv bias
        for (int i = threadIdx.x; i < 4096; i += 256) {
            float v = (i < 2048) ? bq[i] : (i < 3072) ? bk[i - 2048] : bv[i - 3072];
            bcat[i] = v;
        }
        return;
    }
    const float* src; ushort_t* dst; int base;
    if (bid < 4096)       { src = hs; dst = Xb;              base = bid; }
    else if (bid < 6144)  { src = Wq; dst = Wcat;            base = bid - 4096; }
    else if (bid < 7168)  { src = Wk; dst = Wcat + 4194304;  base = bid - 6144; }
    else if (bid < 8192)  { src = Wv; dst = Wcat + 6291456;  base = bid - 7168; }
    else if (bid < 10240) { src = Wo; dst = Wo16;            base = bid - 8192; }
    else                  { src = Rm; dst = Rbf;             base = bid - 10240; }
    int i = base * 2048 + threadIdx.x * 8;
    float4 v0 = *reinterpret_cast<const float4*>(src + i);
    float4 v1 = *reinterpret_cast<const float4*>(src + i + 4);
    ushort_t o[8];
    o[0] = f2bf(v0.x); o[1] = f2bf(v0.y); o[2] = f2bf(v0.z); o[3] = f2bf(v0.w);
    o[4] = f2bf(v1.x); o[5] = f2bf(v1.y); o[6] = f2bf(v1.z); o[7] = f2bf(v1.w);
    *reinterpret_cast<uint4*>(dst + i) = *reinterpret_cast<const uint4*>(o);
}

// ================= 8-phase BMx256 GEMM (T1+T2+T3+T4+T5) ==================
// Verified R6 structure — unchanged this round.
#define CLOSE_PLAIN __builtin_amdgcn_s_barrier()
#define CLOSE_VM(nn) do { asm volatile("s_waitcnt vmcnt(%0)" :: "n"(nn) : "memory"); \
                          __builtin_amdgcn_s_barrier(); } while (0)

template<int BM, int MBLK, int NBLK, int KC, bool STORE_BF16>
__global__ __launch_bounds__(512, 2) void gemm8p_kernel(
    const ushort_t* __restrict__ A, const ushort_t* __restrict__ B,
    const float* __restrict__ bias, void* __restrict__ C,
    const int M, const int N)
{
    constexpr int NT  = KC / 64;
    constexpr int NI  = NT / 2;
    constexpr int MF2 = BM / 64;
    constexpr int NFR = BM / 32;
    constexpr int AH  = BM * 64;
    constexpr int SH  = BM / 128;
    constexpr int BUF = 2 * AH + 32768;
    constexpr int TI  = 2 * SH + 4;
    static_assert(NT % 2 == 0 && NI >= 3, "need even NT >= 6");
    __shared__ alignas(16) char lds[2 * BUF];

    const int tid  = threadIdx.x;
    const int wid  = tid >> 6;
    const int lane = tid & 63;
    const int wm = wid >> 2, wn = wid & 3;

    constexpr int XN  = NBLK / 8;
    constexpr int NXR = 8 / XN;
    constexpr int RH  = MBLK / NXR;
    const int x  = blockIdx.x & 7;
    const int kb = blockIdx.x >> 3;
    const int mb = (x % NXR) * RH + (kb >> 3);
    const int nb = (x / NXR) * 8 + (kb & 7);
    const int am0 = mb * BM, bn0 = nb * 256;

    const int sr3 = tid >> 3;
    const int c8  = tid & 7;
    const int cs  = c8 ^ (sr3 & 7);
    const long K2 = (long)KC * 2;
    const char* agp = (const char*)A + (size_t)(am0 + sr3) * K2 + cs * 16;
    const char* bgp = (const char*)B + (size_t)(bn0 + sr3) * K2 + cs * 16;
    const int ldsw = wid << 10;

    const int fr = lane & 15, fc = lane >> 4;
    const int sw0 = ((fc)     ^ (fr & 7)) * 16;
    const int sw1 = ((4 + fc) ^ (fr & 7)) * 16;
    const int abase = wm * AH + fr * 128;
    const int bbase = 2 * AH + wn * 8192 + fr * 128;

    f32x4 acc[NFR][4] = {};
    bf16x8 bf[4];

    auto stage_half = [&](const char* gp, int rowoff, int bufb, int off,
                          long kof, int niss) {
        char* lp = lds + bufb + off + ldsw;
        const char* g = gp + (size_t)rowoff * K2 + kof;
#pragma unroll
        for (int i = 0; i < niss; ++i)
            async16(g + (size_t)(i * 64) * K2, lp + i * 8192);
    };
#define SA0(T) stage_half(agp, 0,      ((T) & 1) * BUF, 0,          (long)(T) * 128, SH)
#define SA1(T) stage_half(agp, BM / 2, ((T) & 1) * BUF, AH,         (long)(T) * 128, SH)
#define SB0(T) stage_half(bgp, 0,      ((T) & 1) * BUF, 2 * AH,     (long)(T) * 128, 2)
#define SB1(T) stage_half(bgp, 128,    ((T) & 1) * BUF, 2 * AH + 16384, (long)(T) * 128, 2)

#define PH(h, kc, bufb, STG, CLOSE) do {                                      \
    const char* lp_ = lds + (bufb);                                           \
    const int sw_ = (kc) ? sw1 : sw0;                                         \
    if ((h) == 0) {                                                           \
        _Pragma("unroll") for (int n = 0; n < 4; ++n)                         \
            bf[n] = *(const bf16x8*)(lp_ + bbase + n * 2048 + sw_);           \
    }                                                                         \
    bf16x8 af_[MF2];                                                          \
    _Pragma("unroll") for (int j = 0; j < MF2; ++j)                           \
        af_[j] = *(const bf16x8*)(lp_ + abase + ((h) * MF2 + j) * 2048 + sw_);\
    STG;                                                                      \
    __builtin_amdgcn_s_barrier();                                             \
    asm volatile("s_waitcnt lgkmcnt(0)" ::: "memory");                        \
    __builtin_amdgcn_s_setprio(1);                                            \
    _Pragma("unroll") for (int j = 0; j < MF2; ++j)                           \
    _Pragma("unroll") for (int n = 0; n < 4; ++n)                             \
        acc[(h) * MF2 + j][n] = __builtin_amdgcn_mfma_f32_16x16x32_bf16(      \
            af_[j], bf[n], acc[(h) * MF2 + j][n], 0, 0, 0);                   \
    __builtin_amdgcn_s_setprio(0);                                            \
    CLOSE;                                                                    \
} while (0)

    SA0(0); SA1(0); SB0(0); SB1(0);
    SA0(1); SA1(1); SB0(1); SB1(1);
    wait_barrier<TI>();

    PH(0, 0, 0,    (void)0,  CLOSE_PLAIN);
    PH(1, 0, 0,    (void)0,  CLOSE_PLAIN);
    PH(0, 1, 0,    (void)0,  CLOSE_PLAIN);
    PH(1, 1, 0,    SB0(2),   CLOSE_VM(2));
    PH(0, 0, BUF,  SB1(2),   CLOSE_PLAIN);
    PH(1, 0, BUF,  SA0(2),   CLOSE_PLAIN);
    PH(0, 1, BUF,  SA1(2),   CLOSE_PLAIN);
    PH(1, 1, BUF,  SB0(3),   CLOSE_VM(2));

    for (int i = 1; i <= NI - 2; ++i) {
        const int t = 2 * i;
        PH(0, 0, 0,    SB1(t + 1), CLOSE_PLAIN);
        PH(1, 0, 0,    SA0(t + 1), CLOSE_PLAIN);
        PH(0, 1, 0,    SA1(t + 1), CLOSE_PLAIN);
        PH(1, 1, 0,    SB0(t + 2), CLOSE_VM(2));
        PH(0, 0, BUF,  SB1(t + 2), CLOSE_PLAIN);
        PH(1, 0, BUF,  SA0(t + 2), CLOSE_PLAIN);
        PH(0, 1, BUF,  SA1(t + 2), CLOSE_PLAIN);
        PH(1, 1, BUF,  SB0(t + 3), CLOSE_VM(2));
    }

    {
        constexpr int T1 = NT - 1;
        PH(0, 0, 0,    SB1(T1),  CLOSE_PLAIN);
        PH(1, 0, 0,    SA0(T1),  CLOSE_PLAIN);
        PH(0, 1, 0,    SA1(T1),  CLOSE_PLAIN);
        PH(1, 1, 0,    (void)0,  CLOSE_VM(0));
        PH(0, 0, BUF,  (void)0,  CLOSE_PLAIN);
        PH(1, 0, BUF,  (void)0,  CLOSE_PLAIN);
        PH(0, 1, BUF,  (void)0,  CLOSE_PLAIN);
        PH(1, 1, BUF,  (void)0,  CLOSE_PLAIN);
    }

    const int crow0 = fc << 2;
#pragma unroll
    for (int m = 0; m < NFR; ++m) {
        const int row_b = am0 + wm * (BM / 2) + m * 16 + crow0;
#pragma unroll
        for (int n = 0; n < 4; ++n) {
            const int col = bn0 + wn * 64 + n * 16 + fr;
            const float bs = bias[col];
#pragma unroll
            for (int r = 0; r < 4; ++r) {
                const float v = acc[m][n][r] + bs;
                if (STORE_BF16)
                    ((ushort_t*)C)[(size_t)(row_b + r) * N + col] = f2bf(v);
                else
                    ((float*)C)[(size_t)(row_b + r) * N + col] = v;
            }
        }
    }
#undef PH
#undef SA0
#undef SA1
#undef SB0
#undef SB1
}

// ========== fused attention: rope+norm -> R-projection -> sin/cos ==========
// ========== -> A = qp.kp^T (MFMA) -> out = 2*A*v -> scrambled ctx ==========
// One block per token, 256 thr (4 waves). All intermediates stay in LDS.
// xnb/fpb padded to 136 (272B row stride: 16B-aligned, 2-way banks = free).
__global__ __launch_bounds__(256) void fused_attn_kernel(
    const ushort_t* __restrict__ qkv, const ushort_t* __restrict__ Rbf,
    ushort_t* __restrict__ ctx)
{
    __shared__ ushort_t xnb[32][136];   // roped+normalized q(0-15),k(16-23), 24-31 zero
    __shared__ ushort_t fpb[32][136];   // feats [sin|cos]/sqrt(F)
    __shared__ float vsm[8][132];
    __shared__ float Am[16][20];

    const int tok = blockIdx.x;
    const int b = tok >> 11, s = tok & 2047;
    const int tid = threadIdx.x;
    const int wid = tid >> 6, lane = tid & 63;
    const ushort_t* row = qkv + (size_t)tok * 4096;

    // --- stage A: rope + unit-normalize -> xnb; stage v -> vsm ---
    float invf = exp2f(-(float)lane * (13.287712379549449f / 64.0f));
    float ang = (float)s * invf;
    float sn, cs;
    sincosf(ang, &sn, &cs);
#pragma unroll
    for (int i = 0; i < 6; ++i) {
        int vec = wid * 6 + i;
        int base = (vec < 16) ? vec * 128 : 2048 + (vec - 16) * 128;
        float a = bf2f(row[base + lane]);
        float c = bf2f(row[base + lane + 64]);
        float ra = a * cs - c * sn;
        float rc = c * cs + a * sn;
        float ss2 = ra * ra + rc * rc;
#pragma unroll
        for (int off = 32; off; off >>= 1) ss2 += __shfl_xor(ss2, off);
        float inv = 1.0f / fmaxf(sqrtf(ss2), 1e-6f);
        xnb[vec][lane]      = f2bf(ra * inv);
        xnb[vec][lane + 64] = f2bf(rc * inv);
    }
    for (int idx = tid; idx < 1024; idx += 256) {
        xnb[24 + (idx >> 7)][idx & 127] = 0;              // zero pad rows
        vsm[idx >> 7][idx & 127] = bf2f(row[3072 + idx]);
    }
    __syncthreads();

    // --- stage B: p = xn @ R^T via MFMA (wave w owns e-tile w), sin/cos -> fpb ---
    {
        const int fr = lane & 15, fc = lane >> 4;
        f32x4 pacc[2] = {};
#pragma unroll
        for (int kc = 0; kc < 4; ++kc) {
            // B frag: R rows (feats) read directly from global (L1-resident, 16 KB)
            bf16x8 bfrag = *reinterpret_cast<const bf16x8*>(
                Rbf + (wid * 16 + fr) * 128 + kc * 32 + fc * 8);
            bf16x8 a0 = *reinterpret_cast<const bf16x8*>(&xnb[fr][kc * 32 + fc * 8]);
            bf16x8 a1 = *reinterpret_cast<const bf16x8*>(&xnb[16 + fr][kc * 32 + fc * 8]);
            pacc[0] = __builtin_amdgcn_mfma_f32_16x16x32_bf16(a0, bfrag, pacc[0], 0, 0, 0);
            pacc[1] = __builtin_amdgcn_mfma_f32_16x16x32_bf16(a1, bfrag, pacc[1], 0, 0, 0);
        }
        const int e = wid * 16 + fr;   // output col = lane&15 within this e-tile
#pragma unroll
        for (int m = 0; m < 2; ++m)
#pragma unroll
            for (int r = 0; r < 4; ++r) {
                int vec = m * 16 + fc * 4 + r;            // output row
                float sp, cp;
                sincosf(pacc[m][r], &sp, &cp);
                fpb[vec][e]      = f2bf(sp * 0.08838834764831845f);
                fpb[vec][e + 64] = f2bf(cp * 0.08838834764831845f);
            }
    }
    __syncthreads();

    // --- stage C: Am[q][hk] = 2 * <qp[q], kp[hk]> via one-wave MFMA ---
    if (wid == 0) {
        const int fr = lane & 15, fc = lane >> 4;
        f32x4 aacc = {};
#pragma unroll
        for (int kc = 0; kc < 4; ++kc) {
            bf16x8 qa = *reinterpret_cast<const bf16x8*>(&fpb[fr][kc * 32 + fc * 8]);
            bf16x8 ka = *reinterpret_cast<const bf16x8*>(&fpb[16 + fr][kc * 32 + fc * 8]);
            aacc = __builtin_amdgcn_mfma_f32_16x16x32_bf16(qa, ka, aacc, 0, 0, 0);
        }
        if (fr < 8)    // cols 8-15 come from zeroed/junk rows — discard
#pragma unroll
            for (int r = 0; r < 4; ++r)
                Am[fc * 4 + r][fr] = 2.0f * aacc[r];
    }
    __syncthreads();

    // --- stage D: out[h][d] = sum_hk Am[h][hk] * v[hk][d]; scrambled store ---
    for (int idx = tid; idx < 2048; idx += 256) {
        int h = idx >> 7, d = idx & 127;
        float acc = 0.f;
#pragma unroll
        for (int hk = 0; hk < 8; ++hk) acc = fmaf(Am[h][hk], vsm[hk][d], acc);
        int orow = (b << 11) + (h << 7) + (s >> 4);
        int ocol = ((s & 15) << 7) + d;
        ctx[(size_t)orow * 2048 + ocol] = f2bf(acc);
    }
}

// ---------- launch ----------
extern "C" void kernel_launch(void* const* d_in, const int* in_sizes, int n_in,
                              void* d_out, int out_size, void* d_ws, size_t ws_size,
                              hipStream_t stream)
{
    const float* hs = (const float*)d_in[0];
    const float* Wq = (const float*)d_in[1];
    const float* bq = (const float*)d_in[2];
    const float* Wk = (const float*)d_in[3];
    const float* bk = (const float*)d_in[4];
    const float* Wv = (const float*)d_in[5];
    const float* bv = (const float*)d_in[6];
    const float* Wo = (const float*)d_in[7];
    const float* bo = (const float*)d_in[8];
    const float* Rm = (const float*)d_in[9];
    float* out = (float*)d_out;

    char* ws = (char*)d_ws;
    ushort_t* Xb   = (ushort_t*)(ws);                 // 4096x2048 bf16
    ushort_t* Wcat = (ushort_t*)(ws + 16777216);      // 4096x2048 bf16 (Wq;Wk;Wv)
    ushort_t* Wo16 = (ushort_t*)(ws + 33554432);      // 2048x2048 bf16
    ushort_t* qkv  = (ushort_t*)(ws + 41943040);      // 4096x4096 bf16
    ushort_t* ctx  = (ushort_t*)(ws + 75497472);      // 4096x2048 bf16 (scrambled)
    float*    bcat = (float*)   (ws + 92274688);      // 4096 f32
    ushort_t* Rbf  = (ushort_t*)(ws + 92291072);      // 64x128 bf16

    cast_all_kernel<<<10245, 256, 0, stream>>>(hs, Wq, Wk, Wv, Wo, Rm,
                                               bq, bk, bv,
                                               Xb, Wcat, Wo16, Rbf, bcat);

    // qkv = X @ [Wq;Wk;Wv]^T + bcat   (M=4096, N=4096, K=2048) — 8-phase 256x256
    gemm8p_kernel<256, 16, 16, 2048, true><<<256, 512, 0, stream>>>(
        Xb, Wcat, bcat, qkv, 4096, 4096);

    // fused rope+norm+feats+head-contraction -> scrambled ctx
    fused_attn_kernel<<<4096, 256, 0, stream>>>(qkv, Rbf, ctx);

    // out = ctx @ Wo^T + bo   (M=4096, N=2048, K=2048) — 8-phase 128x256
    gemm8p_kernel<128, 32, 8, 2048, false><<<256, 512, 0, stream>>>(
        ctx, Wo16, bo, out, 4096, 2048);
}